// Round 13
// baseline (694.949 us; speedup 1.0000x reference)
//
#include <hip/hip_runtime.h>
#include <cstddef>
#include <cstdint>

#define CDIV(a,b) (((a)+(b)-1)/(b))
#define PAD8(x) ((((x)+7)/8)*8)
#define NEG_SLOPE 0.2f

typedef unsigned short u16;
typedef __attribute__((ext_vector_type(8))) short bf16x8;
typedef __attribute__((ext_vector_type(4))) float f32x4;

// ---------- bf16 helpers (explicit RNE, hi/lo split: v ~= hi + lo, ~17 mantissa bits) ----------
__device__ __forceinline__ u16 bf16_rne(float v){
  unsigned u = __float_as_uint(v);
  unsigned r = (u + 0x7FFFu + ((u >> 16) & 1u)) >> 16;
  return (u16)r;
}
__device__ __forceinline__ float bf16_to_f(u16 h){
  return __uint_as_float(((unsigned)h) << 16);
}
__device__ __forceinline__ void f2hilo(float v, u16& h, u16& l){
  h = bf16_rne(v);
  float r = v - bf16_to_f(h);
  l = bf16_rne(r);
}
// interleaved word: (hi<<16)|lo ; value = asfloat(w&0xFFFF0000) + asfloat(w<<16)
__device__ __forceinline__ float dec_w(unsigned w){
  return __uint_as_float(w & 0xFFFF0000u) + __uint_as_float(w << 16);
}

// ---------- tile-packed operand layout (round-8, verified; GEMM A/B operands only) ----
// Matrix [rows][K] stored as bricks: 128-row block r0, k-tile t (BK=32) -> contiguous
// 4096 u16 (8KB). Element (rr,k) at phys chunk (s+(rr>>1))&3 (s=(k&31)>>3): LDS bank
// swizzle PRE-BAKED, GEMM staging is a pure linear 8KB copy (ideal DRAM bursts).
__device__ __forceinline__ size_t pk_off(int row, int k, int nbk){
  int r0 = row >> 7, rr = row & 127;
  int t = k >> 5, kk = k & 31;
  int s = kk >> 3, w = kk & 7;
  int phys = (s + (rr >> 1)) & 3;
  return ((size_t)(r0 * nbk + t) * 128 + rr) * 32 + phys * 8 + w;
}

__device__ __forceinline__ float sigmf(float x){ return 1.f / (1.f + expf(-x)); }

// ---------- async global->LDS, 16B per lane ----------
__device__ __forceinline__ void gload16(const void* g, void* l){
  __builtin_amdgcn_global_load_lds((const __attribute__((address_space(1))) void*)g,
                                   (__attribute__((address_space(3))) void*)l, 16, 0, 0);
}

// =====================================================================================
// Fused hi/lo MFMA GEMM (round-8/10 proven core — 128x128 tile, 4 waves, BK=32,
// double-buffered LDS, counted vmcnt depth-2 prefetch).
// BLO=true  (3-phase): C = AhBh + AlBh + AhBl  (full hi/lo; LDS 64KB, 2 blocks/CU)
// BLO=false (2-phase): C = AhBh + AlBh          (weights bf16-only; error ~2e-4/GEMM;
//            LDS 48KB -> 3 blocks/CU, 6 loads/stage, 32 MFMA/tile)
// Operands tile-packed (pk_off): stage = linear 8KB copies. Grid (m-blocks %8 padded,
// n-blocks): column-siblings share an XCD -> A fetched ~once per XCD L2.
// NOTE (rounds 7+11): 256^2 tile at 1 block/CU regresses (lockstep waves expose every
// barrier stall). Do not retry without the full 8-phase fine interleave.
// Epilogues: (a) f32 C (+bias), (b) packed hi/lo and/or LINEAR u32 interleaved
// (+bias, optional tanh), (c) fused LSTM (gate-interleaved B; writes c f32 +
// packed h hi/lo + linear u32 h for the next hop's gather/alpha).
// =====================================================================================
template<bool BLO>
__global__ __launch_bounds__(256, 2) void mfma_gemm(
    const u16* __restrict__ Ah0, const u16* __restrict__ Al0,
    const u16* __restrict__ Bh0, const u16* __restrict__ Bl0,
    const u16* __restrict__ Ah1, const u16* __restrict__ Al1,
    const u16* __restrict__ Bh1, const u16* __restrict__ Bl1,
    int npairs, int M, int N, int K,
    const float* __restrict__ bias, float* __restrict__ Cf,
    u16* __restrict__ outHi, u16* __restrict__ outLo, unsigned* __restrict__ outW,
    const float* __restrict__ cIn, float* __restrict__ cOut,
    u16* __restrict__ hH, u16* __restrict__ hL, unsigned* __restrict__ hW,
    int lstm_first, int tanh_out)
{
  constexpr int BUFS = BLO ? 16384 : 12288;   // u16 units per LDS buffer
  if ((int)(blockIdx.x * 128) >= M) return;   // pad-%8 guard (block-uniform)
  __shared__ u16 smem[2 * BUFS];  // per buf: Ah@0 Al@4096 Bh@8192 [Bl@12288 if BLO]
  const int tid = threadIdx.x;
  const int lane = tid & 63, wv = tid >> 6;
  const int l15 = lane & 15, lq = lane >> 4;
  const int wr = wv >> 1, wc = wv & 1;
  const int bm = blockIdx.x * 128, bn = blockIdx.y * 128;
  const int nbk = K >> 5, NT = npairs * nbk;
  const size_t Abase = (size_t)(bm >> 7) * nbk * 4096;
  const size_t Bbase = (size_t)(bn >> 7) * nbk * 4096;

  f32x4 acc[4][4];
  #pragma unroll
  for (int m = 0; m < 4; m++)
    #pragma unroll
    for (int n = 0; n < 4; n++) acc[m][n] = (f32x4){0.f, 0.f, 0.f, 0.f};

  // staging: thread's chunk c = i*256+tid -> linear 16B at brick offset c*16
  size_t goff[2]; int ldso2[2];
  #pragma unroll
  for (int i = 0; i < 2; i++){
    goff[i]  = (size_t)(i * 256 + tid) * 8;        // u16 units, contiguous
    ldso2[i] = (i * 256 + (tid & 192)) * 8;        // wave-uniform LDS base
  }

  // fragment read offsets (u16 units within a buffer); phys chunk = (lq + (r>>1)) & 3
  int aoff[4], boff[4];
  #pragma unroll
  for (int m = 0; m < 4; m++){
    int r = wr * 64 + m * 16 + l15;
    aoff[m] = r * 32 + ((lq + (r >> 1)) & 3) * 8;
  }
  #pragma unroll
  for (int n = 0; n < 4; n++){
    int r = wc * 64 + n * 16 + l15;
    boff[n] = r * 32 + ((lq + (r >> 1)) & 3) * 8;
  }

  auto stage = [&](int buf, int t){
    int q = (npairs > 1 && t >= nbk) ? 1 : 0;
    const u16* A_h = q ? Ah1 : Ah0;  const u16* A_l = q ? Al1 : Al0;
    const u16* B_h = q ? Bh1 : Bh0;  const u16* B_l = q ? Bl1 : Bl0;
    int tl = q ? t - nbk : t;
    size_t ab = Abase + (size_t)tl * 4096;
    size_t bb = Bbase + (size_t)tl * 4096;
    u16* sb = smem + buf * BUFS;
    #pragma unroll
    for (int i = 0; i < 2; i++){
      gload16(A_h + ab + goff[i], sb + ldso2[i]);
      gload16(A_l + ab + goff[i], sb + 4096 + ldso2[i]);
      gload16(B_h + bb + goff[i], sb + 8192 + ldso2[i]);
      if (BLO) gload16(B_l + bb + goff[i], sb + 12288 + ldso2[i]);
    }
  };

  stage(0, 0);                  // 8 (BLO) / 6 loads/wave outstanding
  int cur = 0;
  #pragma unroll 1
  for (int t = 0; t < NT; t++){
    if (t + 1 < NT){
      stage(cur ^ 1, t + 1);    // old loads + new in flight
      if (BLO) asm volatile("s_waitcnt vmcnt(8)" ::: "memory");  // tile-t landed
      else     asm volatile("s_waitcnt vmcnt(6)" ::: "memory");
    } else {
      asm volatile("s_waitcnt vmcnt(0)" ::: "memory");
    }
    __builtin_amdgcn_sched_barrier(0);
    __builtin_amdgcn_s_barrier();        // tile-t visible to all waves
    __builtin_amdgcn_sched_barrier(0);
    const u16* sb = smem + cur * BUFS;
    bf16x8 ah[4], al[4], bh[4], bl[4];
    #pragma unroll
    for (int m = 0; m < 4; m++){
      ah[m] = *(const bf16x8*)(sb + aoff[m]);
      al[m] = *(const bf16x8*)(sb + 4096 + aoff[m]);
    }
    #pragma unroll
    for (int n = 0; n < 4; n++){
      bh[n] = *(const bf16x8*)(sb + 8192 + boff[n]);
      if (BLO) bl[n] = *(const bf16x8*)(sb + 12288 + boff[n]);
    }
    #pragma unroll
    for (int m = 0; m < 4; m++)
      #pragma unroll
      for (int n = 0; n < 4; n++){
        acc[m][n] = __builtin_amdgcn_mfma_f32_16x16x32_bf16(ah[m], bh[n], acc[m][n], 0, 0, 0);
        acc[m][n] = __builtin_amdgcn_mfma_f32_16x16x32_bf16(al[m], bh[n], acc[m][n], 0, 0, 0);
        if (BLO)
          acc[m][n] = __builtin_amdgcn_mfma_f32_16x16x32_bf16(ah[m], bl[n], acc[m][n], 0, 0, 0);
      }
    __builtin_amdgcn_sched_barrier(0);
    __builtin_amdgcn_s_barrier();        // buf[cur] released; NO vmcnt drain
    cur ^= 1;
  }

  // epilogue: C/D layout col=lane&15, row=(lane>>4)*4+j (m89/m91-verified)
  const int rb = bm + wr * 64 + lq * 4;
  if (cOut){
    // LSTM mode: lane owns channel ch; n-frag index == gate (i,f,g,o)
    const int ch = (bn >> 2) + wc * 16 + l15;
    #pragma unroll
    for (int m = 0; m < 4; m++){
      #pragma unroll
      for (int j = 0; j < 4; j++){
        int row = rb + m * 16 + j;
        if (row >= M) continue;
        float i_ = acc[m][0][j], f_ = acc[m][1][j], g_ = acc[m][2][j], o_ = acc[m][3][j];
        float si = sigmf(i_), tg = tanhf(g_), so = sigmf(o_);
        size_t loff = (size_t)row * 256 + ch;
        float cn = lstm_first ? si * tg : sigmf(f_) * cIn[loff] + si * tg;
        float hn = so * tanhf(cn);
        cOut[loff] = cn;
        u16 hh, hl; f2hilo(hn, hh, hl);
        size_t pko = pk_off(row, ch, 8);
        hH[pko] = hh; hL[pko] = hl;
        if (hW) hW[loff] = ((unsigned)hh << 16) | (unsigned)hl;   // linear copy
      }
    }
  } else {
    const int cb = bn + wc * 64 + l15;
    #pragma unroll
    for (int n = 0; n < 4; n++){
      int col = cb + n * 16;
      float bv = bias ? bias[col] : 0.f;
      #pragma unroll
      for (int m = 0; m < 4; m++){
        #pragma unroll
        for (int j = 0; j < 4; j++){
          int row = rb + m * 16 + j;
          if (row >= M) continue;
          float v = acc[m][n][j] + bv;
          if (tanh_out) v = tanhf(v);
          if (Cf) Cf[(size_t)row * N + col] = v;
          if (outHi || outW){
            u16 hh, hl; f2hilo(v, hh, hl);
            if (outHi){
              size_t pko = pk_off(row, col, 8);
              outHi[pko] = hh; outLo[pko] = hl;
            }
            if (outW) outW[(size_t)row * 256 + col] = ((unsigned)hh << 16) | (unsigned)hl;
          }
        }
      }
    }
  }
}

// ---------- feats f32 [60000][128] -> packed hi/lo bf16 (nbk=4), 4 elems/thread ----------
__global__ __launch_bounds__(256) void cvt_feats(const float* __restrict__ in,
    u16* __restrict__ hi, u16* __restrict__ lo, int nrow){
  int i = blockIdx.x * 256 + threadIdx.x;       // quad index
  int row = i >> 5, k4 = (i & 31) * 4;
  if (row >= nrow) return;
  float4 v = *(const float4*)(in + (size_t)row * 128 + k4);
  ushort4 h4, l4;
  f2hilo(v.x, h4.x, l4.x); f2hilo(v.y, h4.y, l4.y);
  f2hilo(v.z, h4.z, l4.z); f2hilo(v.w, h4.w, l4.w);
  size_t off = pk_off(row, k4, 4);              // w in {0,4}: ushort4 stays in-chunk
  *(ushort4*)(hi + off) = h4;
  *(ushort4*)(lo + off) = l4;
}

// ---------- one-shot weight prep: transpose/permute + PACKED hi/lo bf16 ----------
// Transposed sections (Win/Wsrc/Wout) indexed so READS are coalesced.
// W_ih/W_hh rows PERMUTED to gate-interleaved layout: orig row (gate*256+ch)
// -> n' = (ch>>4)*64 + gate*16 + (ch&15), so the GEMM epilogue can fuse LSTM.
__global__ __launch_bounds__(256) void prep_w(const float* __restrict__ Win,
    const float* __restrict__ Wsrc, const float* __restrict__ Wih,
    const float* __restrict__ Whh, const float* __restrict__ Wout,
    u16* WinH, u16* WinL, u16* WsH, u16* WsL,
    u16* IhH, u16* IhL, u16* HhH, u16* HhL, u16* WoH, u16* WoL){
  int idx = blockIdx.x * 256 + threadIdx.x;
  float v; u16 *ph, *pl; size_t off;
  if (idx < 32768){                       // WinT [256][128] <- Win[128][256]; nbk=4
    int n = idx & 255, k = idx >> 8;      // coalesced read over n
    v = Win[k * 256 + n]; ph = WinH; pl = WinL; off = pk_off(n, k, 4);
  } else if (idx < 229376){               // WsT [3][256][256] <- Wsrc^T; nbk=8
    int t = idx - 32768; int hop = t >> 16, r = t & 65535, n = r & 255, k = r >> 8;
    v = Wsrc[hop * 65536 + k * 256 + n]; ph = WsH; pl = WsL;
    off = (size_t)hop * 65536 + pk_off(n, k, 8);
  } else if (idx < 1015808){              // W_ih [3][1024][256], gate-interleaved; nbk=8
    int t = idx - 229376;
    int hop = t >> 18, r = (t >> 8) & 1023, k = t & 255;
    int gate = r >> 8, ch = r & 255;
    int np = ((ch >> 4) << 6) + (gate << 4) + (ch & 15);
    v = Wih[t]; ph = IhH; pl = IhL;
    off = (size_t)hop * 262144 + pk_off(np, k, 8);
  } else if (idx < 1802240){              // W_hh, same permutation
    int t = idx - 1015808;
    int hop = t >> 18, r = (t >> 8) & 1023, k = t & 255;
    int gate = r >> 8, ch = r & 255;
    int np = ((ch >> 4) << 6) + (gate << 4) + (ch & 15);
    v = Whh[t]; ph = HhH; pl = HhL;
    off = (size_t)hop * 262144 + pk_off(np, k, 8);
  } else if (idx < 1835008){              // WoT [128][256] <- Wout^T; nbk=8
    int t = idx - 1802240; int n = t & 127, k = t >> 7;  // coalesced read over n
    v = Wout[k * 128 + n]; ph = WoH; pl = WoL; off = pk_off(n, k, 8);
  } else return;
  u16 hh, hl; f2hilo(v, hh, hl);
  ph[off] = hh; pl[off] = hl;
}

// ---------- w_s[hop] = Wsrc[hop]@a_s, w_d[hop] = Wdst[hop]@a_d (row dots, f32) ----------
__global__ __launch_bounds__(256) void prep_wvec(const float* __restrict__ Wsrc,
    const float* __restrict__ Wdst, const float* __restrict__ as_,
    const float* __restrict__ ad_, float* __restrict__ wsv, float* __restrict__ wdv){
  int wid = blockIdx.x * 4 + (threadIdx.x >> 6), lane = threadIdx.x & 63;
  if (wid >= 6 * 256) return;
  int vec = wid >> 8, i = wid & 255;
  int hop = vec >> 1; bool isd = vec & 1;
  const float* Wrow = (isd ? Wdst : Wsrc) + (size_t)hop * 65536 + (size_t)i * 256;
  const float* a = (isd ? ad_ : as_) + hop * 256;
  float4 w4 = *(const float4*)(Wrow + lane * 4);
  float4 a4 = *(const float4*)(a + lane * 4);
  float v = w4.x * a4.x + w4.y * a4.y + w4.z * a4.z + w4.w * a4.w;
  #pragma unroll
  for (int off = 32; off; off >>= 1) v += __shfl_down(v, off);
  if (!lane) (isd ? wdv : wsv)[hop * 256 + i] = v;
}

// ---------- alpha from LINEAR interleaved x: coalesced uint4 row reads ----------
__global__ __launch_bounds__(256) void alpha_mv(const unsigned* __restrict__ xW,
    const float* __restrict__ wsv, const float* __restrict__ wdv,
    float* __restrict__ as_out, float* __restrict__ ad_out, int ns, int nd){
  int wid = blockIdx.x * 4 + (threadIdx.x >> 6), lane = threadIdx.x & 63;
  if (wid >= ns + nd) return;
  bool isd = wid >= ns;
  int row = isd ? wid - ns : wid;
  uint4 w = *(const uint4*)(xW + (size_t)row * 256 + lane * 4);
  const float* wv = isd ? wdv : wsv;
  float4 w4 = *(const float4*)(wv + lane * 4);
  float v = dec_w(w.x) * w4.x + dec_w(w.y) * w4.y + dec_w(w.z) * w4.z + dec_w(w.w) * w4.w;
  #pragma unroll
  for (int off2 = 32; off2; off2 >>= 1) v += __shfl_down(v, off2);
  if (!lane) (isd ? ad_out : as_out)[row] = v;
}

// ---------- edges + self-loops: leaky-relu alpha -> e=exp(alpha) directly, degree ----
// NO-MAX softmax (round-12, exact up to fp noise: alphas O(1), softmax shift-invariant)
__global__ __launch_bounds__(256) void edge_a(const int* __restrict__ src,
    const int* __restrict__ dst, const float* __restrict__ as_, const float* __restrict__ ad_,
    float* __restrict__ e_edge, float* __restrict__ e_self,
    int* __restrict__ cnt, int E, int nd){
  int i = blockIdx.x * 256 + threadIdx.x;
  if (i < E){
    int s = src[i], d = dst[i];
    float al = as_[s] + ad_[d];
    al = al > 0.f ? al : NEG_SLOPE * al;
    e_edge[i] = expf(al);
    atomicAdd(&cnt[d], 1);
  } else if (i < E + nd){
    int j = i - E;
    float al = as_[j] + ad_[j];
    al = al > 0.f ? al : NEG_SLOPE * al;
    e_self[j] = expf(al);
  }
}

// ---------- scan, 2 dispatches ----------
__global__ __launch_bounds__(256) void scan_part(const int* __restrict__ cnt,
    int* __restrict__ part, int n){
  __shared__ int ws_[4];
  int lane = threadIdx.x & 63, wv = threadIdx.x >> 6;
  int i = blockIdx.x * 256 + threadIdx.x;
  int v = (i < n) ? cnt[i] : 0;
  #pragma unroll
  for (int off = 32; off; off >>= 1) v += __shfl_down(v, off);
  if (!lane) ws_[wv] = v;
  __syncthreads();
  if (!threadIdx.x) part[blockIdx.x] = ws_[0] + ws_[1] + ws_[2] + ws_[3];
}
__global__ __launch_bounds__(256) void scan_fin(const int* __restrict__ cnt,
    const int* __restrict__ part, int* __restrict__ base, int* __restrict__ cursor,
    int n, int nb){
  __shared__ int ps[128];
  __shared__ int wtot[4];
  int t = threadIdx.x;
  if (t < 128) ps[t] = (t < nb) ? part[t] : 0;
  __syncthreads();
  #pragma unroll
  for (int off = 1; off < 128; off <<= 1){
    int v = (t < 128 && t >= off) ? ps[t - off] : 0;
    __syncthreads();
    if (t < 128) ps[t] += v;
    __syncthreads();
  }
  int lane = t & 63, wv = t >> 6;
  int i = blockIdx.x * 256 + t;
  int v = (i < n) ? cnt[i] : 0;
  int incl = v;
  #pragma unroll
  for (int off = 1; off < 64; off <<= 1){
    int s = __shfl_up(incl, off);
    if (lane >= off) incl += s;
  }
  if (lane == 63) wtot[wv] = incl;
  __syncthreads();
  int woff = blockIdx.x ? ps[blockIdx.x - 1] : 0;
  for (int w = 0; w < wv; w++) woff += wtot[w];
  int excl = woff + incl - v;
  if (i < n){ base[i] = excl; cursor[i] = excl; }
}

// ---------- CSR fill (e already computed in edge_a) ----------
__global__ __launch_bounds__(256) void edge_b(const int* __restrict__ src,
    const int* __restrict__ dst, const float* __restrict__ e_edge,
    int* __restrict__ cursor, int* __restrict__ csr_src, float* __restrict__ csr_e, int E){
  int e = blockIdx.x * 256 + threadIdx.x;
  if (e >= E) return;
  int d = dst[e];
  int pos = atomicAdd(&cursor[d], 1);
  csr_src[pos] = src[e];
  csr_e[pos] = e_edge[e];
}

// ---------- gather: agg[j] = (sum_e w_e x[src] + w_self x[j]) / sum w ----------
// x from LINEAR interleaved u32 rows (1KB contiguous per edge, coalesced uint4/lane)
// with 8-deep independent-load unroll (MLP). Output packed (GEMM A-operand).
__global__ __launch_bounds__(256) void gather_agg(const unsigned* __restrict__ xW,
    const int* __restrict__ base, const int* __restrict__ cnt,
    const int* __restrict__ csr_src, const float* __restrict__ csr_e,
    const float* __restrict__ e_self,
    u16* __restrict__ aggH, u16* __restrict__ aggL, int n){
  int wv = threadIdx.x >> 6, lane = threadIdx.x & 63;
  int j = blockIdx.x * 4 + wv;
  if (j >= n) return;
  int b0 = base[j], cn = cnt[j];
  float a0 = 0.f, a1 = 0.f, a2 = 0.f, a3 = 0.f, ds = 0.f;
  int k = 0;
  for (; k + 8 <= cn; k += 8){
    int ss[8]; float ee[8]; uint4 ww[8];
    #pragma unroll
    for (int u = 0; u < 8; u++){ ss[u] = csr_src[b0 + k + u]; ee[u] = csr_e[b0 + k + u]; }
    #pragma unroll
    for (int u = 0; u < 8; u++) ww[u] = *(const uint4*)(xW + (size_t)ss[u] * 256 + lane * 4);
    #pragma unroll
    for (int u = 0; u < 8; u++){
      float e = ee[u];
      a0 += e * dec_w(ww[u].x); a1 += e * dec_w(ww[u].y);
      a2 += e * dec_w(ww[u].z); a3 += e * dec_w(ww[u].w);
      ds += e;
    }
  }
  for (; k < cn; k++){
    int s = csr_src[b0 + k];
    float e = csr_e[b0 + k];
    uint4 w = *(const uint4*)(xW + (size_t)s * 256 + lane * 4);
    a0 += e * dec_w(w.x); a1 += e * dec_w(w.y);
    a2 += e * dec_w(w.z); a3 += e * dec_w(w.w);
    ds += e;
  }
  float es = e_self[j];
  {
    uint4 w = *(const uint4*)(xW + (size_t)j * 256 + lane * 4);
    a0 += es * dec_w(w.x); a1 += es * dec_w(w.y);
    a2 += es * dec_w(w.z); a3 += es * dec_w(w.w);
    ds += es;
  }
  float inv = 1.f / ds;
  ushort4 H4, L4;
  f2hilo(a0 * inv, H4.x, L4.x); f2hilo(a1 * inv, H4.y, L4.y);
  f2hilo(a2 * inv, H4.z, L4.z); f2hilo(a3 * inv, H4.w, L4.w);
  size_t off = pk_off(j, lane * 4, 8);
  *(ushort4*)(aggH + off) = H4;
  *(ushort4*)(aggL + off) = L4;
}

extern "C" void kernel_launch(void* const* d_in, const int* in_sizes, int n_in,
                              void* d_out, int out_size, void* d_ws, size_t ws_size,
                              hipStream_t stream){
  const float* feats   = (const float*)d_in[0];
  const float* Win     = (const float*)d_in[1];
  const float* b_in    = (const float*)d_in[2];
  const float* Wsrc    = (const float*)d_in[3];
  const float* Wdst    = (const float*)d_in[4];
  const float* att_src = (const float*)d_in[5];
  const float* att_dst = (const float*)d_in[6];
  const float* gat_b   = (const float*)d_in[7];
  const float* W_ih    = (const float*)d_in[8];
  const float* W_hh    = (const float*)d_in[9];
  const float* Wout    = (const float*)d_in[10];
  const float* b_out   = (const float*)d_in[11];
  const int* srcs[3] = {(const int*)d_in[12], (const int*)d_in[14], (const int*)d_in[16]};
  const int* dsts[3] = {(const int*)d_in[13], (const int*)d_in[15], (const int*)d_in[17]};
  (void)in_sizes; (void)n_in; (void)out_size; (void)ws_size;

  const int ns_a[3] = {60000, 30000, 15000};
  const int nd_a[3] = {30000, 15000, 7500};
  const int E_a[3]  = {480000, 240000, 120000};

  // ---- workspace layout (~231 MiB), aliasing lifetime-checked ----
  char* w = (char*)d_ws;
  unsigned* xW = (unsigned*)(w + 0);              // linear interleaved x rows, 60032x256 u32
  u16* featsH  = (u16*)(w + 61500000);            // packed 60032x128; dead after inproj
  u16* featsL  = (u16*)(w + 77000000);
  float* c     = (float*)(w + 61500000);          // [30000][256] f32; alias feats
                                                  // (feats dead after inproj; c first written hop0 gates)
  u16* aggH    = (u16*)(w + 92500000);            // packed 30080x256
  u16* aggL    = (u16*)(w + 108000000);
  u16* hAH     = (u16*)(w + 123500000);           // packed h ping-pong A
  u16* hAL     = (u16*)(w + 139000000);
  u16* hBH     = (u16*)(w + 154500000);           // set B
  u16* hBL     = (u16*)(w + 170000000);
  u16* xbH     = (u16*)(w + 185500000);
  u16* xbL     = (u16*)(w + 201000000);
  u16* WinH = (u16*)(w + 216500000);  u16* WinL = WinH + 32768;
  u16* WsH  = WinL + 32768;           u16* WsL  = WsH + 196608;
  u16* IhH  = WsL + 196608;           u16* IhL  = IhH + 786432;
  u16* HhH  = IhL + 786432;           u16* HhL  = HhH + 786432;
  u16* WoH  = HhL + 786432;           u16* WoL  = WoH + 32768;
  float* wsv = (float*)(w + 224200000); float* wdv = wsv + 768;
  float* alpha_s = wdv + 768;
  float* alpha_d = alpha_s + 60000;
  float* e_edge  = alpha_d + 30000;               // per-edge exp(alpha)
  float* e_self  = e_edge + 480000;               // per-node self exp(alpha)
  int* cnt       = (int*)(e_self + 30000);
  int* base      = cnt + 30000;
  int* cursor    = base + 30000;
  int* part      = cursor + 30000;                // scan partials (<=128)
  int* csr_src   = part + 256;
  float* csr_e   = (float*)(csr_src + 480000);

  // ---- one-time prep (inputs only) ----
  prep_w<<<7168, 256, 0, stream>>>(Win, Wsrc, W_ih, W_hh, Wout,
      WinH, WinL, WsH, WsL, IhH, IhL, HhH, HhL, WoH, WoL);
  prep_wvec<<<384, 256, 0, stream>>>(Wsrc, Wdst, att_src, att_dst, wsv, wdv);
  cvt_feats<<<7500, 256, 0, stream>>>(feats, featsH, featsL, 60000);

  // ---- input projection (3-phase): x0 (linear interleaved) = feats @ Win + b_in ----
  {
    dim3 g(PAD8(CDIV(60000, 128)), 2);
    mfma_gemm<true><<<g, 256, 0, stream>>>(featsH, featsL, WinH, WinL,
        nullptr, nullptr, nullptr, nullptr, 1, 60000, 256, 128,
        b_in, nullptr, nullptr, nullptr, xW, nullptr, nullptr,
        nullptr, nullptr, nullptr, 0, 0);
  }

  u16* hCurH = hAH; u16* hCurL = hAL;   // packed h from previous hop (pair-1 A-op)
  for (int hop = 0; hop < 3; hop++){
    const int ns = ns_a[hop], nd = nd_a[hop], E = E_a[hop];
    const int nb = CDIV(nd, 256);
    hipMemsetAsync(cnt, 0, (size_t)nd * 4, stream);

    alpha_mv<<<CDIV(ns + nd, 4), 256, 0, stream>>>(xW, wsv + hop * 256, wdv + hop * 256,
        alpha_s, alpha_d, ns, nd);
    edge_a<<<CDIV(E + nd, 256), 256, 0, stream>>>(srcs[hop], dsts[hop], alpha_s, alpha_d,
        e_edge, e_self, cnt, E, nd);
    scan_part<<<nb, 256, 0, stream>>>(cnt, part, nd);
    scan_fin<<<nb, 256, 0, stream>>>(cnt, part, base, cursor, nd, nb);
    edge_b<<<CDIV(E, 256), 256, 0, stream>>>(srcs[hop], dsts[hop], e_edge,
        cursor, csr_src, csr_e, E);
    gather_agg<<<CDIV(nd, 4), 256, 0, stream>>>(xW, base, cnt, csr_src, csr_e,
        e_self, aggH, aggL, nd);

    // xb(packed) = tanh(agg @ WsrcT + gat_b)   [2-phase: weights bf16]
    {
      dim3 g(PAD8(CDIV(nd, 128)), 2);
      mfma_gemm<false><<<g, 256, 0, stream>>>(aggH, aggL, WsH + (size_t)hop * 65536, WsL + (size_t)hop * 65536,
          nullptr, nullptr, nullptr, nullptr, 1, nd, 256, 256,
          gat_b + hop * 256, nullptr, xbH, xbL, nullptr, nullptr, nullptr,
          nullptr, nullptr, nullptr, 0, 1);
    }

    // gates GEMM + fused LSTM [2-phase: weights bf16]; h: packed ping-pong (A-op)
    // + linear xW (next hop's gather/alpha; dead after hop 1 -> skip at hop 2)
    u16* hNewH = (hop == 0) ? hAH : (hCurH == hAH ? hBH : hAH);
    u16* hNewL = (hop == 0) ? hAL : (hCurL == hAL ? hBL : hAL);
    {
      dim3 g(PAD8(CDIV(nd, 128)), 8);
      mfma_gemm<false><<<g, 256, 0, stream>>>(xbH, xbL, IhH + (size_t)hop * 262144, IhL + (size_t)hop * 262144,
          hCurH, hCurL, HhH + (size_t)hop * 262144, HhL + (size_t)hop * 262144,
          hop ? 2 : 1, nd, 1024, 256,
          nullptr, nullptr, nullptr, nullptr, nullptr,
          c, c, hNewH, hNewL, hop < 2 ? xW : nullptr, hop == 0 ? 1 : 0, 0);
    }
    hCurH = hNewH; hCurL = hNewL;
  }

  // ---- output projection (3-phase, N=128): d_out = h @ Wout + b_out ----
  {
    dim3 g(PAD8(CDIV(7500, 128)), 1);
    mfma_gemm<true><<<g, 256, 0, stream>>>(hCurH, hCurL, WoH, WoL,
        nullptr, nullptr, nullptr, nullptr, 1, 7500, 128, 256,
        b_out, (float*)d_out, nullptr, nullptr, nullptr, nullptr, nullptr,
        nullptr, nullptr, nullptr, 0, 0);
  }
}

// Round 14
// 625.725 us; speedup vs baseline: 1.1106x; 1.1106x over previous
//
#include <hip/hip_runtime.h>
#include <cstddef>
#include <cstdint>

#define CDIV(a,b) (((a)+(b)-1)/(b))
#define PAD8(x) ((((x)+7)/8)*8)
#define NEG_SLOPE 0.2f

typedef unsigned short u16;
typedef __attribute__((ext_vector_type(8))) short bf16x8;
typedef __attribute__((ext_vector_type(4))) float f32x4;

// ---------- bf16 helpers (explicit RNE, hi/lo split: v ~= hi + lo, ~17 mantissa bits) ----------
__device__ __forceinline__ u16 bf16_rne(float v){
  unsigned u = __float_as_uint(v);
  unsigned r = (u + 0x7FFFu + ((u >> 16) & 1u)) >> 16;
  return (u16)r;
}
__device__ __forceinline__ float bf16_to_f(u16 h){
  return __uint_as_float(((unsigned)h) << 16);
}
__device__ __forceinline__ void f2hilo(float v, u16& h, u16& l){
  h = bf16_rne(v);
  float r = v - bf16_to_f(h);
  l = bf16_rne(r);
}
// interleaved word: (hi<<16)|lo ; value = asfloat(w&0xFFFF0000) + asfloat(w<<16)
__device__ __forceinline__ float dec_w(unsigned w){
  return __uint_as_float(w & 0xFFFF0000u) + __uint_as_float(w << 16);
}

// ---------- tile-packed operand layout (round-8, verified; GEMM A/B operands only) ----
// Matrix [rows][K] stored as bricks: 128-row block r0, k-tile t (BK=32) -> contiguous
// 4096 u16 (8KB). Element (rr,k) at phys chunk (s+(rr>>1))&3 (s=(k&31)>>3): LDS bank
// swizzle PRE-BAKED, GEMM staging is a pure linear 8KB copy (ideal DRAM bursts).
__device__ __forceinline__ size_t pk_off(int row, int k, int nbk){
  int r0 = row >> 7, rr = row & 127;
  int t = k >> 5, kk = k & 31;
  int s = kk >> 3, w = kk & 7;
  int phys = (s + (rr >> 1)) & 3;
  return ((size_t)(r0 * nbk + t) * 128 + rr) * 32 + phys * 8 + w;
}

__device__ __forceinline__ float sigmf(float x){ return 1.f / (1.f + expf(-x)); }

// ---------- async global->LDS, 16B per lane ----------
__device__ __forceinline__ void gload16(const void* g, void* l){
  __builtin_amdgcn_global_load_lds((const __attribute__((address_space(1))) void*)g,
                                   (__attribute__((address_space(3))) void*)l, 16, 0, 0);
}

// =====================================================================================
// Fused hi/lo MFMA GEMM (round-8/10 proven core — 128x128 tile, 4 waves, BK=32,
// double-buffered LDS, counted vmcnt depth-2 prefetch).
// BLO=true  (3-phase): C = AhBh + AlBh + AhBl  (full hi/lo; LDS 64KB, 2 blocks/CU)
// BLO=false (2-phase): C = AhBh + AlBh          (weights bf16-only; error ~2e-4/GEMM,
//            validated round 13: absmax unchanged; LDS 48KB -> 3 blocks/CU)
// ROUND-14 BISECT: 2-phase used for the GATES GEMM ONLY (round 13 applied it to xb too
// and total regressed +79us despite gates improving -17us; isolating).
// Operands tile-packed (pk_off): stage = linear 8KB copies. Grid (m-blocks %8 padded,
// n-blocks): column-siblings share an XCD -> A fetched ~once per XCD L2.
// NOTE (rounds 7+11): 256^2 tile at 1 block/CU regresses (lockstep waves expose every
// barrier stall). Do not retry without the full 8-phase fine interleave.
// =====================================================================================
template<bool BLO>
__global__ __launch_bounds__(256, 2) void mfma_gemm(
    const u16* __restrict__ Ah0, const u16* __restrict__ Al0,
    const u16* __restrict__ Bh0, const u16* __restrict__ Bl0,
    const u16* __restrict__ Ah1, const u16* __restrict__ Al1,
    const u16* __restrict__ Bh1, const u16* __restrict__ Bl1,
    int npairs, int M, int N, int K,
    const float* __restrict__ bias, float* __restrict__ Cf,
    u16* __restrict__ outHi, u16* __restrict__ outLo, unsigned* __restrict__ outW,
    const float* __restrict__ cIn, float* __restrict__ cOut,
    u16* __restrict__ hH, u16* __restrict__ hL, unsigned* __restrict__ hW,
    int lstm_first, int tanh_out)
{
  constexpr int BUFS = BLO ? 16384 : 12288;   // u16 units per LDS buffer
  if ((int)(blockIdx.x * 128) >= M) return;   // pad-%8 guard (block-uniform)
  __shared__ u16 smem[2 * BUFS];  // per buf: Ah@0 Al@4096 Bh@8192 [Bl@12288 if BLO]
  const int tid = threadIdx.x;
  const int lane = tid & 63, wv = tid >> 6;
  const int l15 = lane & 15, lq = lane >> 4;
  const int wr = wv >> 1, wc = wv & 1;
  const int bm = blockIdx.x * 128, bn = blockIdx.y * 128;
  const int nbk = K >> 5, NT = npairs * nbk;
  const size_t Abase = (size_t)(bm >> 7) * nbk * 4096;
  const size_t Bbase = (size_t)(bn >> 7) * nbk * 4096;

  f32x4 acc[4][4];
  #pragma unroll
  for (int m = 0; m < 4; m++)
    #pragma unroll
    for (int n = 0; n < 4; n++) acc[m][n] = (f32x4){0.f, 0.f, 0.f, 0.f};

  // staging: thread's chunk c = i*256+tid -> linear 16B at brick offset c*16
  size_t goff[2]; int ldso2[2];
  #pragma unroll
  for (int i = 0; i < 2; i++){
    goff[i]  = (size_t)(i * 256 + tid) * 8;        // u16 units, contiguous
    ldso2[i] = (i * 256 + (tid & 192)) * 8;        // wave-uniform LDS base
  }

  // fragment read offsets (u16 units within a buffer); phys chunk = (lq + (r>>1)) & 3
  int aoff[4], boff[4];
  #pragma unroll
  for (int m = 0; m < 4; m++){
    int r = wr * 64 + m * 16 + l15;
    aoff[m] = r * 32 + ((lq + (r >> 1)) & 3) * 8;
  }
  #pragma unroll
  for (int n = 0; n < 4; n++){
    int r = wc * 64 + n * 16 + l15;
    boff[n] = r * 32 + ((lq + (r >> 1)) & 3) * 8;
  }

  auto stage = [&](int buf, int t){
    int q = (npairs > 1 && t >= nbk) ? 1 : 0;
    const u16* A_h = q ? Ah1 : Ah0;  const u16* A_l = q ? Al1 : Al0;
    const u16* B_h = q ? Bh1 : Bh0;  const u16* B_l = q ? Bl1 : Bl0;
    int tl = q ? t - nbk : t;
    size_t ab = Abase + (size_t)tl * 4096;
    size_t bb = Bbase + (size_t)tl * 4096;
    u16* sb = smem + buf * BUFS;
    #pragma unroll
    for (int i = 0; i < 2; i++){
      gload16(A_h + ab + goff[i], sb + ldso2[i]);
      gload16(A_l + ab + goff[i], sb + 4096 + ldso2[i]);
      gload16(B_h + bb + goff[i], sb + 8192 + ldso2[i]);
      if (BLO) gload16(B_l + bb + goff[i], sb + 12288 + ldso2[i]);
    }
  };

  stage(0, 0);                  // 8 (BLO) / 6 loads/wave outstanding
  int cur = 0;
  #pragma unroll 1
  for (int t = 0; t < NT; t++){
    if (t + 1 < NT){
      stage(cur ^ 1, t + 1);    // old loads + new in flight
      if (BLO) asm volatile("s_waitcnt vmcnt(8)" ::: "memory");  // tile-t landed
      else     asm volatile("s_waitcnt vmcnt(6)" ::: "memory");
    } else {
      asm volatile("s_waitcnt vmcnt(0)" ::: "memory");
    }
    __builtin_amdgcn_sched_barrier(0);
    __builtin_amdgcn_s_barrier();        // tile-t visible to all waves
    __builtin_amdgcn_sched_barrier(0);
    const u16* sb = smem + cur * BUFS;
    bf16x8 ah[4], al[4], bh[4], bl[4];
    #pragma unroll
    for (int m = 0; m < 4; m++){
      ah[m] = *(const bf16x8*)(sb + aoff[m]);
      al[m] = *(const bf16x8*)(sb + 4096 + aoff[m]);
    }
    #pragma unroll
    for (int n = 0; n < 4; n++){
      bh[n] = *(const bf16x8*)(sb + 8192 + boff[n]);
      if (BLO) bl[n] = *(const bf16x8*)(sb + 12288 + boff[n]);
    }
    #pragma unroll
    for (int m = 0; m < 4; m++)
      #pragma unroll
      for (int n = 0; n < 4; n++){
        acc[m][n] = __builtin_amdgcn_mfma_f32_16x16x32_bf16(ah[m], bh[n], acc[m][n], 0, 0, 0);
        acc[m][n] = __builtin_amdgcn_mfma_f32_16x16x32_bf16(al[m], bh[n], acc[m][n], 0, 0, 0);
        if (BLO)
          acc[m][n] = __builtin_amdgcn_mfma_f32_16x16x32_bf16(ah[m], bl[n], acc[m][n], 0, 0, 0);
      }
    __builtin_amdgcn_sched_barrier(0);
    __builtin_amdgcn_s_barrier();        // buf[cur] released; NO vmcnt drain
    cur ^= 1;
  }

  // epilogue: C/D layout col=lane&15, row=(lane>>4)*4+j (m89/m91-verified)
  const int rb = bm + wr * 64 + lq * 4;
  if (cOut){
    // LSTM mode: lane owns channel ch; n-frag index == gate (i,f,g,o)
    const int ch = (bn >> 2) + wc * 16 + l15;
    #pragma unroll
    for (int m = 0; m < 4; m++){
      #pragma unroll
      for (int j = 0; j < 4; j++){
        int row = rb + m * 16 + j;
        if (row >= M) continue;
        float i_ = acc[m][0][j], f_ = acc[m][1][j], g_ = acc[m][2][j], o_ = acc[m][3][j];
        float si = sigmf(i_), tg = tanhf(g_), so = sigmf(o_);
        size_t loff = (size_t)row * 256 + ch;
        float cn = lstm_first ? si * tg : sigmf(f_) * cIn[loff] + si * tg;
        float hn = so * tanhf(cn);
        cOut[loff] = cn;
        u16 hh, hl; f2hilo(hn, hh, hl);
        size_t pko = pk_off(row, ch, 8);
        hH[pko] = hh; hL[pko] = hl;
        if (hW) hW[loff] = ((unsigned)hh << 16) | (unsigned)hl;   // linear copy
      }
    }
  } else {
    const int cb = bn + wc * 64 + l15;
    #pragma unroll
    for (int n = 0; n < 4; n++){
      int col = cb + n * 16;
      float bv = bias ? bias[col] : 0.f;
      #pragma unroll
      for (int m = 0; m < 4; m++){
        #pragma unroll
        for (int j = 0; j < 4; j++){
          int row = rb + m * 16 + j;
          if (row >= M) continue;
          float v = acc[m][n][j] + bv;
          if (tanh_out) v = tanhf(v);
          if (Cf) Cf[(size_t)row * N + col] = v;
          if (outHi || outW){
            u16 hh, hl; f2hilo(v, hh, hl);
            if (outHi){
              size_t pko = pk_off(row, col, 8);
              outHi[pko] = hh; outLo[pko] = hl;
            }
            if (outW) outW[(size_t)row * 256 + col] = ((unsigned)hh << 16) | (unsigned)hl;
          }
        }
      }
    }
  }
}

// ---------- feats f32 [60000][128] -> packed hi/lo bf16 (nbk=4), 4 elems/thread ----------
__global__ __launch_bounds__(256) void cvt_feats(const float* __restrict__ in,
    u16* __restrict__ hi, u16* __restrict__ lo, int nrow){
  int i = blockIdx.x * 256 + threadIdx.x;       // quad index
  int row = i >> 5, k4 = (i & 31) * 4;
  if (row >= nrow) return;
  float4 v = *(const float4*)(in + (size_t)row * 128 + k4);
  ushort4 h4, l4;
  f2hilo(v.x, h4.x, l4.x); f2hilo(v.y, h4.y, l4.y);
  f2hilo(v.z, h4.z, l4.z); f2hilo(v.w, h4.w, l4.w);
  size_t off = pk_off(row, k4, 4);              // w in {0,4}: ushort4 stays in-chunk
  *(ushort4*)(hi + off) = h4;
  *(ushort4*)(lo + off) = l4;
}

// ---------- one-shot weight prep: transpose/permute + PACKED hi/lo bf16 ----------
// Transposed sections (Win/Wsrc/Wout) indexed so READS are coalesced.
// W_ih/W_hh rows PERMUTED to gate-interleaved layout: orig row (gate*256+ch)
// -> n' = (ch>>4)*64 + gate*16 + (ch&15), so the GEMM epilogue can fuse LSTM.
__global__ __launch_bounds__(256) void prep_w(const float* __restrict__ Win,
    const float* __restrict__ Wsrc, const float* __restrict__ Wih,
    const float* __restrict__ Whh, const float* __restrict__ Wout,
    u16* WinH, u16* WinL, u16* WsH, u16* WsL,
    u16* IhH, u16* IhL, u16* HhH, u16* HhL, u16* WoH, u16* WoL){
  int idx = blockIdx.x * 256 + threadIdx.x;
  float v; u16 *ph, *pl; size_t off;
  if (idx < 32768){                       // WinT [256][128] <- Win[128][256]; nbk=4
    int n = idx & 255, k = idx >> 8;      // coalesced read over n
    v = Win[k * 256 + n]; ph = WinH; pl = WinL; off = pk_off(n, k, 4);
  } else if (idx < 229376){               // WsT [3][256][256] <- Wsrc^T; nbk=8
    int t = idx - 32768; int hop = t >> 16, r = t & 65535, n = r & 255, k = r >> 8;
    v = Wsrc[hop * 65536 + k * 256 + n]; ph = WsH; pl = WsL;
    off = (size_t)hop * 65536 + pk_off(n, k, 8);
  } else if (idx < 1015808){              // W_ih [3][1024][256], gate-interleaved; nbk=8
    int t = idx - 229376;
    int hop = t >> 18, r = (t >> 8) & 1023, k = t & 255;
    int gate = r >> 8, ch = r & 255;
    int np = ((ch >> 4) << 6) + (gate << 4) + (ch & 15);
    v = Wih[t]; ph = IhH; pl = IhL;
    off = (size_t)hop * 262144 + pk_off(np, k, 8);
  } else if (idx < 1802240){              // W_hh, same permutation
    int t = idx - 1015808;
    int hop = t >> 18, r = (t >> 8) & 1023, k = t & 255;
    int gate = r >> 8, ch = r & 255;
    int np = ((ch >> 4) << 6) + (gate << 4) + (ch & 15);
    v = Whh[t]; ph = HhH; pl = HhL;
    off = (size_t)hop * 262144 + pk_off(np, k, 8);
  } else if (idx < 1835008){              // WoT [128][256] <- Wout^T; nbk=8
    int t = idx - 1802240; int n = t & 127, k = t >> 7;  // coalesced read over n
    v = Wout[k * 128 + n]; ph = WoH; pl = WoL; off = pk_off(n, k, 8);
  } else return;
  u16 hh, hl; f2hilo(v, hh, hl);
  ph[off] = hh; pl[off] = hl;
}

// ---------- w_s[hop] = Wsrc[hop]@a_s, w_d[hop] = Wdst[hop]@a_d (row dots, f32) ----------
__global__ __launch_bounds__(256) void prep_wvec(const float* __restrict__ Wsrc,
    const float* __restrict__ Wdst, const float* __restrict__ as_,
    const float* __restrict__ ad_, float* __restrict__ wsv, float* __restrict__ wdv){
  int wid = blockIdx.x * 4 + (threadIdx.x >> 6), lane = threadIdx.x & 63;
  if (wid >= 6 * 256) return;
  int vec = wid >> 8, i = wid & 255;
  int hop = vec >> 1; bool isd = vec & 1;
  const float* Wrow = (isd ? Wdst : Wsrc) + (size_t)hop * 65536 + (size_t)i * 256;
  const float* a = (isd ? ad_ : as_) + hop * 256;
  float4 w4 = *(const float4*)(Wrow + lane * 4);
  float4 a4 = *(const float4*)(a + lane * 4);
  float v = w4.x * a4.x + w4.y * a4.y + w4.z * a4.z + w4.w * a4.w;
  #pragma unroll
  for (int off = 32; off; off >>= 1) v += __shfl_down(v, off);
  if (!lane) (isd ? wdv : wsv)[hop * 256 + i] = v;
}

// ---------- alpha from LINEAR interleaved x: coalesced uint4 row reads ----------
__global__ __launch_bounds__(256) void alpha_mv(const unsigned* __restrict__ xW,
    const float* __restrict__ wsv, const float* __restrict__ wdv,
    float* __restrict__ as_out, float* __restrict__ ad_out, int ns, int nd){
  int wid = blockIdx.x * 4 + (threadIdx.x >> 6), lane = threadIdx.x & 63;
  if (wid >= ns + nd) return;
  bool isd = wid >= ns;
  int row = isd ? wid - ns : wid;
  uint4 w = *(const uint4*)(xW + (size_t)row * 256 + lane * 4);
  const float* wv = isd ? wdv : wsv;
  float4 w4 = *(const float4*)(wv + lane * 4);
  float v = dec_w(w.x) * w4.x + dec_w(w.y) * w4.y + dec_w(w.z) * w4.z + dec_w(w.w) * w4.w;
  #pragma unroll
  for (int off2 = 32; off2; off2 >>= 1) v += __shfl_down(v, off2);
  if (!lane) (isd ? ad_out : as_out)[row] = v;
}

// ---------- edges + self-loops: leaky-relu alpha -> e=exp(alpha) directly, degree ----
// NO-MAX softmax (round-12, exact up to fp noise: alphas O(1), softmax shift-invariant)
__global__ __launch_bounds__(256) void edge_a(const int* __restrict__ src,
    const int* __restrict__ dst, const float* __restrict__ as_, const float* __restrict__ ad_,
    float* __restrict__ e_edge, float* __restrict__ e_self,
    int* __restrict__ cnt, int E, int nd){
  int i = blockIdx.x * 256 + threadIdx.x;
  if (i < E){
    int s = src[i], d = dst[i];
    float al = as_[s] + ad_[d];
    al = al > 0.f ? al : NEG_SLOPE * al;
    e_edge[i] = expf(al);
    atomicAdd(&cnt[d], 1);
  } else if (i < E + nd){
    int j = i - E;
    float al = as_[j] + ad_[j];
    al = al > 0.f ? al : NEG_SLOPE * al;
    e_self[j] = expf(al);
  }
}

// ---------- scan, 2 dispatches ----------
__global__ __launch_bounds__(256) void scan_part(const int* __restrict__ cnt,
    int* __restrict__ part, int n){
  __shared__ int ws_[4];
  int lane = threadIdx.x & 63, wv = threadIdx.x >> 6;
  int i = blockIdx.x * 256 + threadIdx.x;
  int v = (i < n) ? cnt[i] : 0;
  #pragma unroll
  for (int off = 32; off; off >>= 1) v += __shfl_down(v, off);
  if (!lane) ws_[wv] = v;
  __syncthreads();
  if (!threadIdx.x) part[blockIdx.x] = ws_[0] + ws_[1] + ws_[2] + ws_[3];
}
__global__ __launch_bounds__(256) void scan_fin(const int* __restrict__ cnt,
    const int* __restrict__ part, int* __restrict__ base, int* __restrict__ cursor,
    int n, int nb){
  __shared__ int ps[128];
  __shared__ int wtot[4];
  int t = threadIdx.x;
  if (t < 128) ps[t] = (t < nb) ? part[t] : 0;
  __syncthreads();
  #pragma unroll
  for (int off = 1; off < 128; off <<= 1){
    int v = (t < 128 && t >= off) ? ps[t - off] : 0;
    __syncthreads();
    if (t < 128) ps[t] += v;
    __syncthreads();
  }
  int lane = t & 63, wv = t >> 6;
  int i = blockIdx.x * 256 + t;
  int v = (i < n) ? cnt[i] : 0;
  int incl = v;
  #pragma unroll
  for (int off = 1; off < 64; off <<= 1){
    int s = __shfl_up(incl, off);
    if (lane >= off) incl += s;
  }
  if (lane == 63) wtot[wv] = incl;
  __syncthreads();
  int woff = blockIdx.x ? ps[blockIdx.x - 1] : 0;
  for (int w = 0; w < wv; w++) woff += wtot[w];
  int excl = woff + incl - v;
  if (i < n){ base[i] = excl; cursor[i] = excl; }
}

// ---------- CSR fill (e already computed in edge_a) ----------
__global__ __launch_bounds__(256) void edge_b(const int* __restrict__ src,
    const int* __restrict__ dst, const float* __restrict__ e_edge,
    int* __restrict__ cursor, int* __restrict__ csr_src, float* __restrict__ csr_e, int E){
  int e = blockIdx.x * 256 + threadIdx.x;
  if (e >= E) return;
  int d = dst[e];
  int pos = atomicAdd(&cursor[d], 1);
  csr_src[pos] = src[e];
  csr_e[pos] = e_edge[e];
}

// ---------- gather: agg[j] = (sum_e w_e x[src] + w_self x[j]) / sum w ----------
// x from LINEAR interleaved u32 rows (1KB contiguous per edge, coalesced uint4/lane)
// with 8-deep independent-load unroll (MLP). Output packed (GEMM A-operand).
__global__ __launch_bounds__(256) void gather_agg(const unsigned* __restrict__ xW,
    const int* __restrict__ base, const int* __restrict__ cnt,
    const int* __restrict__ csr_src, const float* __restrict__ csr_e,
    const float* __restrict__ e_self,
    u16* __restrict__ aggH, u16* __restrict__ aggL, int n){
  int wv = threadIdx.x >> 6, lane = threadIdx.x & 63;
  int j = blockIdx.x * 4 + wv;
  if (j >= n) return;
  int b0 = base[j], cn = cnt[j];
  float a0 = 0.f, a1 = 0.f, a2 = 0.f, a3 = 0.f, ds = 0.f;
  int k = 0;
  for (; k + 8 <= cn; k += 8){
    int ss[8]; float ee[8]; uint4 ww[8];
    #pragma unroll
    for (int u = 0; u < 8; u++){ ss[u] = csr_src[b0 + k + u]; ee[u] = csr_e[b0 + k + u]; }
    #pragma unroll
    for (int u = 0; u < 8; u++) ww[u] = *(const uint4*)(xW + (size_t)ss[u] * 256 + lane * 4);
    #pragma unroll
    for (int u = 0; u < 8; u++){
      float e = ee[u];
      a0 += e * dec_w(ww[u].x); a1 += e * dec_w(ww[u].y);
      a2 += e * dec_w(ww[u].z); a3 += e * dec_w(ww[u].w);
      ds += e;
    }
  }
  for (; k < cn; k++){
    int s = csr_src[b0 + k];
    float e = csr_e[b0 + k];
    uint4 w = *(const uint4*)(xW + (size_t)s * 256 + lane * 4);
    a0 += e * dec_w(w.x); a1 += e * dec_w(w.y);
    a2 += e * dec_w(w.z); a3 += e * dec_w(w.w);
    ds += e;
  }
  float es = e_self[j];
  {
    uint4 w = *(const uint4*)(xW + (size_t)j * 256 + lane * 4);
    a0 += es * dec_w(w.x); a1 += es * dec_w(w.y);
    a2 += es * dec_w(w.z); a3 += es * dec_w(w.w);
    ds += es;
  }
  float inv = 1.f / ds;
  ushort4 H4, L4;
  f2hilo(a0 * inv, H4.x, L4.x); f2hilo(a1 * inv, H4.y, L4.y);
  f2hilo(a2 * inv, H4.z, L4.z); f2hilo(a3 * inv, H4.w, L4.w);
  size_t off = pk_off(j, lane * 4, 8);
  *(ushort4*)(aggH + off) = H4;
  *(ushort4*)(aggL + off) = L4;
}

extern "C" void kernel_launch(void* const* d_in, const int* in_sizes, int n_in,
                              void* d_out, int out_size, void* d_ws, size_t ws_size,
                              hipStream_t stream){
  const float* feats   = (const float*)d_in[0];
  const float* Win     = (const float*)d_in[1];
  const float* b_in    = (const float*)d_in[2];
  const float* Wsrc    = (const float*)d_in[3];
  const float* Wdst    = (const float*)d_in[4];
  const float* att_src = (const float*)d_in[5];
  const float* att_dst = (const float*)d_in[6];
  const float* gat_b   = (const float*)d_in[7];
  const float* W_ih    = (const float*)d_in[8];
  const float* W_hh    = (const float*)d_in[9];
  const float* Wout    = (const float*)d_in[10];
  const float* b_out   = (const float*)d_in[11];
  const int* srcs[3] = {(const int*)d_in[12], (const int*)d_in[14], (const int*)d_in[16]};
  const int* dsts[3] = {(const int*)d_in[13], (const int*)d_in[15], (const int*)d_in[17]};
  (void)in_sizes; (void)n_in; (void)out_size; (void)ws_size;

  const int ns_a[3] = {60000, 30000, 15000};
  const int nd_a[3] = {30000, 15000, 7500};
  const int E_a[3]  = {480000, 240000, 120000};

  // ---- workspace layout (~231 MiB), aliasing lifetime-checked ----
  char* w = (char*)d_ws;
  unsigned* xW = (unsigned*)(w + 0);              // linear interleaved x rows, 60032x256 u32
  u16* featsH  = (u16*)(w + 61500000);            // packed 60032x128; dead after inproj
  u16* featsL  = (u16*)(w + 77000000);
  float* c     = (float*)(w + 61500000);          // [30000][256] f32; alias feats
                                                  // (feats dead after inproj; c first written hop0 gates)
  u16* aggH    = (u16*)(w + 92500000);            // packed 30080x256
  u16* aggL    = (u16*)(w + 108000000);
  u16* hAH     = (u16*)(w + 123500000);           // packed h ping-pong A
  u16* hAL     = (u16*)(w + 139000000);
  u16* hBH     = (u16*)(w + 154500000);           // set B
  u16* hBL     = (u16*)(w + 170000000);
  u16* xbH     = (u16*)(w + 185500000);
  u16* xbL     = (u16*)(w + 201000000);
  u16* WinH = (u16*)(w + 216500000);  u16* WinL = WinH + 32768;
  u16* WsH  = WinL + 32768;           u16* WsL  = WsH + 196608;
  u16* IhH  = WsL + 196608;           u16* IhL  = IhH + 786432;
  u16* HhH  = IhL + 786432;           u16* HhL  = HhH + 786432;
  u16* WoH  = HhL + 786432;           u16* WoL  = WoH + 32768;
  float* wsv = (float*)(w + 224200000); float* wdv = wsv + 768;
  float* alpha_s = wdv + 768;
  float* alpha_d = alpha_s + 60000;
  float* e_edge  = alpha_d + 30000;               // per-edge exp(alpha)
  float* e_self  = e_edge + 480000;               // per-node self exp(alpha)
  int* cnt       = (int*)(e_self + 30000);
  int* base      = cnt + 30000;
  int* cursor    = base + 30000;
  int* part      = cursor + 30000;                // scan partials (<=128)
  int* csr_src   = part + 256;
  float* csr_e   = (float*)(csr_src + 480000);

  // ---- one-time prep (inputs only) ----
  prep_w<<<7168, 256, 0, stream>>>(Win, Wsrc, W_ih, W_hh, Wout,
      WinH, WinL, WsH, WsL, IhH, IhL, HhH, HhL, WoH, WoL);
  prep_wvec<<<384, 256, 0, stream>>>(Wsrc, Wdst, att_src, att_dst, wsv, wdv);
  cvt_feats<<<7500, 256, 0, stream>>>(feats, featsH, featsL, 60000);

  // ---- input projection (3-phase): x0 (linear interleaved) = feats @ Win + b_in ----
  {
    dim3 g(PAD8(CDIV(60000, 128)), 2);
    mfma_gemm<true><<<g, 256, 0, stream>>>(featsH, featsL, WinH, WinL,
        nullptr, nullptr, nullptr, nullptr, 1, 60000, 256, 128,
        b_in, nullptr, nullptr, nullptr, xW, nullptr, nullptr,
        nullptr, nullptr, nullptr, 0, 0);
  }

  u16* hCurH = hAH; u16* hCurL = hAL;   // packed h from previous hop (pair-1 A-op)
  for (int hop = 0; hop < 3; hop++){
    const int ns = ns_a[hop], nd = nd_a[hop], E = E_a[hop];
    const int nb = CDIV(nd, 256);
    hipMemsetAsync(cnt, 0, (size_t)nd * 4, stream);

    alpha_mv<<<CDIV(ns + nd, 4), 256, 0, stream>>>(xW, wsv + hop * 256, wdv + hop * 256,
        alpha_s, alpha_d, ns, nd);
    edge_a<<<CDIV(E + nd, 256), 256, 0, stream>>>(srcs[hop], dsts[hop], alpha_s, alpha_d,
        e_edge, e_self, cnt, E, nd);
    scan_part<<<nb, 256, 0, stream>>>(cnt, part, nd);
    scan_fin<<<nb, 256, 0, stream>>>(cnt, part, base, cursor, nd, nb);
    edge_b<<<CDIV(E, 256), 256, 0, stream>>>(srcs[hop], dsts[hop], e_edge,
        cursor, csr_src, csr_e, E);
    gather_agg<<<CDIV(nd, 4), 256, 0, stream>>>(xW, base, cnt, csr_src, csr_e,
        e_self, aggH, aggL, nd);

    // xb(packed) = tanh(agg @ WsrcT + gat_b)   [3-phase — round-12 config]
    {
      dim3 g(PAD8(CDIV(nd, 128)), 2);
      mfma_gemm<true><<<g, 256, 0, stream>>>(aggH, aggL, WsH + (size_t)hop * 65536, WsL + (size_t)hop * 65536,
          nullptr, nullptr, nullptr, nullptr, 1, nd, 256, 256,
          gat_b + hop * 256, nullptr, xbH, xbL, nullptr, nullptr, nullptr,
          nullptr, nullptr, nullptr, 0, 1);
    }

    // gates GEMM + fused LSTM [2-phase: weights bf16 — the round-13 verified win];
    // h: packed ping-pong (A-op) + linear xW (next hop; dead after hop 1)
    u16* hNewH = (hop == 0) ? hAH : (hCurH == hAH ? hBH : hAH);
    u16* hNewL = (hop == 0) ? hAL : (hCurL == hAL ? hBL : hAL);
    {
      dim3 g(PAD8(CDIV(nd, 128)), 8);
      mfma_gemm<false><<<g, 256, 0, stream>>>(xbH, xbL, IhH + (size_t)hop * 262144, IhL + (size_t)hop * 262144,
          hCurH, hCurL, HhH + (size_t)hop * 262144, HhL + (size_t)hop * 262144,
          hop ? 2 : 1, nd, 1024, 256,
          nullptr, nullptr, nullptr, nullptr, nullptr,
          c, c, hNewH, hNewL, hop < 2 ? xW : nullptr, hop == 0 ? 1 : 0, 0);
    }
    hCurH = hNewH; hCurL = hNewL;
  }

  // ---- output projection (3-phase, N=128): d_out = h @ Wout + b_out ----
  {
    dim3 g(PAD8(CDIV(7500, 128)), 1);
    mfma_gemm<true><<<g, 256, 0, stream>>>(hCurH, hCurL, WoH, WoL,
        nullptr, nullptr, nullptr, nullptr, 1, 7500, 128, 256,
        b_out, (float*)d_out, nullptr, nullptr, nullptr, nullptr, nullptr,
        nullptr, nullptr, nullptr, 0, 0);
  }
}

// Round 15
// 609.526 us; speedup vs baseline: 1.1401x; 1.0266x over previous
//
#include <hip/hip_runtime.h>
#include <cstddef>
#include <cstdint>

#define CDIV(a,b) (((a)+(b)-1)/(b))
#define PAD8(x) ((((x)+7)/8)*8)
#define NEG_SLOPE 0.2f

typedef unsigned short u16;
typedef __attribute__((ext_vector_type(8))) short bf16x8;
typedef __attribute__((ext_vector_type(4))) float f32x4;

// ---------- bf16 helpers (explicit RNE, hi/lo split: v ~= hi + lo, ~17 mantissa bits) ----------
__device__ __forceinline__ u16 bf16_rne(float v){
  unsigned u = __float_as_uint(v);
  unsigned r = (u + 0x7FFFu + ((u >> 16) & 1u)) >> 16;
  return (u16)r;
}
__device__ __forceinline__ float bf16_to_f(u16 h){
  return __uint_as_float(((unsigned)h) << 16);
}
__device__ __forceinline__ void f2hilo(float v, u16& h, u16& l){
  h = bf16_rne(v);
  float r = v - bf16_to_f(h);
  l = bf16_rne(r);
}
// interleaved word: (hi<<16)|lo ; value = asfloat(w&0xFFFF0000) + asfloat(w<<16)
__device__ __forceinline__ float dec_w(unsigned w){
  return __uint_as_float(w & 0xFFFF0000u) + __uint_as_float(w << 16);
}

// ---------- tile-packed operand layout (round-8, verified; GEMM A/B operands only) ----
// Matrix [rows][K] stored as bricks: 128-row block r0, k-tile t (BK=32) -> contiguous
// 4096 u16 (8KB). Element (rr,k) at phys chunk (s+(rr>>1))&3 (s=(k&31)>>3): LDS bank
// swizzle PRE-BAKED, GEMM staging is a pure linear 8KB copy (ideal DRAM bursts).
__device__ __forceinline__ size_t pk_off(int row, int k, int nbk){
  int r0 = row >> 7, rr = row & 127;
  int t = k >> 5, kk = k & 31;
  int s = kk >> 3, w = kk & 7;
  int phys = (s + (rr >> 1)) & 3;
  return ((size_t)(r0 * nbk + t) * 128 + rr) * 32 + phys * 8 + w;
}

__device__ __forceinline__ float sigmf(float x){ return 1.f / (1.f + expf(-x)); }

// ---------- async global->LDS, 16B per lane ----------
__device__ __forceinline__ void gload16(const void* g, void* l){
  __builtin_amdgcn_global_load_lds((const __attribute__((address_space(1))) void*)g,
                                   (__attribute__((address_space(3))) void*)l, 16, 0, 0);
}

// =====================================================================================
// Fused hi/lo MFMA GEMM — round-12 proven config, SINGLE untemplated instantiation.
// (Rounds 13/14 added a template<bool> 2-phase variant: the targeted dispatch improved
//  -16us but totals regressed ~+10..+80us — consistent with co-instantiation codegen
//  perturbation of the 3-phase variant [rule #19]. Reverted to the single-variant
//  build that measured the session best, 616us.)
// 128x128 tile, 4 waves, BK=32, double-buffered LDS (64KB -> 2 blocks/CU), counted
// vmcnt(8) depth-2 prefetch. C = sum_pairs (Ah+Al)(Bh+Bl)^T, dropping lo*lo.
// Operands tile-packed (pk_off): stage = linear 8KB copies. Grid (m-blocks %8 padded,
// n-blocks): column-siblings share an XCD -> A fetched ~once per XCD L2.
// NOTE (rounds 7+11): 256^2 tile at 1 block/CU regresses (lockstep waves expose every
// barrier stall). Do not retry without the full 8-phase fine interleave.
// Epilogues: (a) f32 C (+bias), (b) packed hi/lo and/or LINEAR u32 interleaved
// (+bias, optional tanh), (c) fused LSTM (gate-interleaved B; writes c f32 +
// packed h hi/lo + linear u32 h for the next hop's gather/alpha).
// =====================================================================================
__global__ __launch_bounds__(256, 2) void mfma_gemm(
    const u16* __restrict__ Ah0, const u16* __restrict__ Al0,
    const u16* __restrict__ Bh0, const u16* __restrict__ Bl0,
    const u16* __restrict__ Ah1, const u16* __restrict__ Al1,
    const u16* __restrict__ Bh1, const u16* __restrict__ Bl1,
    int npairs, int M, int N, int K,
    const float* __restrict__ bias, float* __restrict__ Cf,
    u16* __restrict__ outHi, u16* __restrict__ outLo, unsigned* __restrict__ outW,
    const float* __restrict__ cIn, float* __restrict__ cOut,
    u16* __restrict__ hH, u16* __restrict__ hL, unsigned* __restrict__ hW,
    int lstm_first, int tanh_out)
{
  if ((int)(blockIdx.x * 128) >= M) return;   // pad-%8 guard (block-uniform)
  __shared__ u16 smem[2 * 16384];  // per buf: Ah@0 Al@4096 Bh@8192 Bl@12288 (u16 units)
  const int tid = threadIdx.x;
  const int lane = tid & 63, wv = tid >> 6;
  const int l15 = lane & 15, lq = lane >> 4;
  const int wr = wv >> 1, wc = wv & 1;
  const int bm = blockIdx.x * 128, bn = blockIdx.y * 128;
  const int nbk = K >> 5, NT = npairs * nbk;
  const size_t Abase = (size_t)(bm >> 7) * nbk * 4096;
  const size_t Bbase = (size_t)(bn >> 7) * nbk * 4096;

  f32x4 acc[4][4];
  #pragma unroll
  for (int m = 0; m < 4; m++)
    #pragma unroll
    for (int n = 0; n < 4; n++) acc[m][n] = (f32x4){0.f, 0.f, 0.f, 0.f};

  // staging: thread's chunk c = i*256+tid -> linear 16B at brick offset c*16
  size_t goff[2]; int ldso2[2];
  #pragma unroll
  for (int i = 0; i < 2; i++){
    goff[i]  = (size_t)(i * 256 + tid) * 8;        // u16 units, contiguous
    ldso2[i] = (i * 256 + (tid & 192)) * 8;        // wave-uniform LDS base
  }

  // fragment read offsets (u16 units within a buffer); phys chunk = (lq + (r>>1)) & 3
  int aoff[4], boff[4];
  #pragma unroll
  for (int m = 0; m < 4; m++){
    int r = wr * 64 + m * 16 + l15;
    aoff[m] = r * 32 + ((lq + (r >> 1)) & 3) * 8;
  }
  #pragma unroll
  for (int n = 0; n < 4; n++){
    int r = wc * 64 + n * 16 + l15;
    boff[n] = r * 32 + ((lq + (r >> 1)) & 3) * 8;
  }

  auto stage = [&](int buf, int t){
    int q = (npairs > 1 && t >= nbk) ? 1 : 0;
    const u16* A_h = q ? Ah1 : Ah0;  const u16* A_l = q ? Al1 : Al0;
    const u16* B_h = q ? Bh1 : Bh0;  const u16* B_l = q ? Bl1 : Bl0;
    int tl = q ? t - nbk : t;
    size_t ab = Abase + (size_t)tl * 4096;
    size_t bb = Bbase + (size_t)tl * 4096;
    u16* sb = smem + buf * 16384;
    #pragma unroll
    for (int i = 0; i < 2; i++){
      gload16(A_h + ab + goff[i], sb + ldso2[i]);
      gload16(A_l + ab + goff[i], sb + 4096 + ldso2[i]);
      gload16(B_h + bb + goff[i], sb + 8192 + ldso2[i]);
      gload16(B_l + bb + goff[i], sb + 12288 + ldso2[i]);
    }
  };

  stage(0, 0);                  // 8 loads/wave outstanding
  int cur = 0;
  #pragma unroll 1
  for (int t = 0; t < NT; t++){
    if (t + 1 < NT){
      stage(cur ^ 1, t + 1);    // +8 -> up to 16 outstanding
      asm volatile("s_waitcnt vmcnt(8)" ::: "memory");   // tile-t landed; t+1 in flight
    } else {
      asm volatile("s_waitcnt vmcnt(0)" ::: "memory");
    }
    __builtin_amdgcn_sched_barrier(0);
    __builtin_amdgcn_s_barrier();        // tile-t visible to all waves
    __builtin_amdgcn_sched_barrier(0);
    const u16* sb = smem + cur * 16384;
    bf16x8 ah[4], al[4], bh[4], bl[4];
    #pragma unroll
    for (int m = 0; m < 4; m++){
      ah[m] = *(const bf16x8*)(sb + aoff[m]);
      al[m] = *(const bf16x8*)(sb + 4096 + aoff[m]);
    }
    #pragma unroll
    for (int n = 0; n < 4; n++){
      bh[n] = *(const bf16x8*)(sb + 8192 + boff[n]);
      bl[n] = *(const bf16x8*)(sb + 12288 + boff[n]);
    }
    #pragma unroll
    for (int m = 0; m < 4; m++)
      #pragma unroll
      for (int n = 0; n < 4; n++){
        acc[m][n] = __builtin_amdgcn_mfma_f32_16x16x32_bf16(ah[m], bh[n], acc[m][n], 0, 0, 0);
        acc[m][n] = __builtin_amdgcn_mfma_f32_16x16x32_bf16(al[m], bh[n], acc[m][n], 0, 0, 0);
        acc[m][n] = __builtin_amdgcn_mfma_f32_16x16x32_bf16(ah[m], bl[n], acc[m][n], 0, 0, 0);
      }
    __builtin_amdgcn_sched_barrier(0);
    __builtin_amdgcn_s_barrier();        // buf[cur] released; NO vmcnt drain
    cur ^= 1;
  }

  // epilogue: C/D layout col=lane&15, row=(lane>>4)*4+j (m89/m91-verified)
  const int rb = bm + wr * 64 + lq * 4;
  if (cOut){
    // LSTM mode: lane owns channel ch; n-frag index == gate (i,f,g,o)
    const int ch = (bn >> 2) + wc * 16 + l15;
    #pragma unroll
    for (int m = 0; m < 4; m++){
      #pragma unroll
      for (int j = 0; j < 4; j++){
        int row = rb + m * 16 + j;
        if (row >= M) continue;
        float i_ = acc[m][0][j], f_ = acc[m][1][j], g_ = acc[m][2][j], o_ = acc[m][3][j];
        float si = sigmf(i_), tg = tanhf(g_), so = sigmf(o_);
        size_t loff = (size_t)row * 256 + ch;
        float cn = lstm_first ? si * tg : sigmf(f_) * cIn[loff] + si * tg;
        float hn = so * tanhf(cn);
        cOut[loff] = cn;
        u16 hh, hl; f2hilo(hn, hh, hl);
        size_t pko = pk_off(row, ch, 8);
        hH[pko] = hh; hL[pko] = hl;
        if (hW) hW[loff] = ((unsigned)hh << 16) | (unsigned)hl;   // linear copy
      }
    }
  } else {
    const int cb = bn + wc * 64 + l15;
    #pragma unroll
    for (int n = 0; n < 4; n++){
      int col = cb + n * 16;
      float bv = bias ? bias[col] : 0.f;
      #pragma unroll
      for (int m = 0; m < 4; m++){
        #pragma unroll
        for (int j = 0; j < 4; j++){
          int row = rb + m * 16 + j;
          if (row >= M) continue;
          float v = acc[m][n][j] + bv;
          if (tanh_out) v = tanhf(v);
          if (Cf) Cf[(size_t)row * N + col] = v;
          if (outHi || outW){
            u16 hh, hl; f2hilo(v, hh, hl);
            if (outHi){
              size_t pko = pk_off(row, col, 8);
              outHi[pko] = hh; outLo[pko] = hl;
            }
            if (outW) outW[(size_t)row * 256 + col] = ((unsigned)hh << 16) | (unsigned)hl;
          }
        }
      }
    }
  }
}

// ---------- feats f32 [60000][128] -> packed hi/lo bf16 (nbk=4), 4 elems/thread ----------
__global__ __launch_bounds__(256) void cvt_feats(const float* __restrict__ in,
    u16* __restrict__ hi, u16* __restrict__ lo, int nrow){
  int i = blockIdx.x * 256 + threadIdx.x;       // quad index
  int row = i >> 5, k4 = (i & 31) * 4;
  if (row >= nrow) return;
  float4 v = *(const float4*)(in + (size_t)row * 128 + k4);
  ushort4 h4, l4;
  f2hilo(v.x, h4.x, l4.x); f2hilo(v.y, h4.y, l4.y);
  f2hilo(v.z, h4.z, l4.z); f2hilo(v.w, h4.w, l4.w);
  size_t off = pk_off(row, k4, 4);              // w in {0,4}: ushort4 stays in-chunk
  *(ushort4*)(hi + off) = h4;
  *(ushort4*)(lo + off) = l4;
}

// ---------- one-shot weight prep: transpose/permute + PACKED hi/lo bf16 ----------
// Transposed sections (Win/Wsrc/Wout) indexed so READS are coalesced.
// W_ih/W_hh rows PERMUTED to gate-interleaved layout: orig row (gate*256+ch)
// -> n' = (ch>>4)*64 + gate*16 + (ch&15), so the GEMM epilogue can fuse LSTM.
__global__ __launch_bounds__(256) void prep_w(const float* __restrict__ Win,
    const float* __restrict__ Wsrc, const float* __restrict__ Wih,
    const float* __restrict__ Whh, const float* __restrict__ Wout,
    u16* WinH, u16* WinL, u16* WsH, u16* WsL,
    u16* IhH, u16* IhL, u16* HhH, u16* HhL, u16* WoH, u16* WoL){
  int idx = blockIdx.x * 256 + threadIdx.x;
  float v; u16 *ph, *pl; size_t off;
  if (idx < 32768){                       // WinT [256][128] <- Win[128][256]; nbk=4
    int n = idx & 255, k = idx >> 8;      // coalesced read over n
    v = Win[k * 256 + n]; ph = WinH; pl = WinL; off = pk_off(n, k, 4);
  } else if (idx < 229376){               // WsT [3][256][256] <- Wsrc^T; nbk=8
    int t = idx - 32768; int hop = t >> 16, r = t & 65535, n = r & 255, k = r >> 8;
    v = Wsrc[hop * 65536 + k * 256 + n]; ph = WsH; pl = WsL;
    off = (size_t)hop * 65536 + pk_off(n, k, 8);
  } else if (idx < 1015808){              // W_ih [3][1024][256], gate-interleaved; nbk=8
    int t = idx - 229376;
    int hop = t >> 18, r = (t >> 8) & 1023, k = t & 255;
    int gate = r >> 8, ch = r & 255;
    int np = ((ch >> 4) << 6) + (gate << 4) + (ch & 15);
    v = Wih[t]; ph = IhH; pl = IhL;
    off = (size_t)hop * 262144 + pk_off(np, k, 8);
  } else if (idx < 1802240){              // W_hh, same permutation
    int t = idx - 1015808;
    int hop = t >> 18, r = (t >> 8) & 1023, k = t & 255;
    int gate = r >> 8, ch = r & 255;
    int np = ((ch >> 4) << 6) + (gate << 4) + (ch & 15);
    v = Whh[t]; ph = HhH; pl = HhL;
    off = (size_t)hop * 262144 + pk_off(np, k, 8);
  } else if (idx < 1835008){              // WoT [128][256] <- Wout^T; nbk=8
    int t = idx - 1802240; int n = t & 127, k = t >> 7;  // coalesced read over n
    v = Wout[k * 128 + n]; ph = WoH; pl = WoL; off = pk_off(n, k, 8);
  } else return;
  u16 hh, hl; f2hilo(v, hh, hl);
  ph[off] = hh; pl[off] = hl;
}

// ---------- w_s[hop] = Wsrc[hop]@a_s, w_d[hop] = Wdst[hop]@a_d (row dots, f32) ----------
__global__ __launch_bounds__(256) void prep_wvec(const float* __restrict__ Wsrc,
    const float* __restrict__ Wdst, const float* __restrict__ as_,
    const float* __restrict__ ad_, float* __restrict__ wsv, float* __restrict__ wdv){
  int wid = blockIdx.x * 4 + (threadIdx.x >> 6), lane = threadIdx.x & 63;
  if (wid >= 6 * 256) return;
  int vec = wid >> 8, i = wid & 255;
  int hop = vec >> 1; bool isd = vec & 1;
  const float* Wrow = (isd ? Wdst : Wsrc) + (size_t)hop * 65536 + (size_t)i * 256;
  const float* a = (isd ? ad_ : as_) + hop * 256;
  float4 w4 = *(const float4*)(Wrow + lane * 4);
  float4 a4 = *(const float4*)(a + lane * 4);
  float v = w4.x * a4.x + w4.y * a4.y + w4.z * a4.z + w4.w * a4.w;
  #pragma unroll
  for (int off = 32; off; off >>= 1) v += __shfl_down(v, off);
  if (!lane) (isd ? wdv : wsv)[hop * 256 + i] = v;
}

// ---------- alpha from LINEAR interleaved x: coalesced uint4 row reads ----------
// Rows < nd need BOTH the src-dot (vs wsv) and dst-dot (vs wdv): compute both in ONE
// row pass (saves re-reading those rows; ~13MB across hops).
__global__ __launch_bounds__(256) void alpha_mv(const unsigned* __restrict__ xW,
    const float* __restrict__ wsv, const float* __restrict__ wdv,
    float* __restrict__ as_out, float* __restrict__ ad_out, int ns, int nd){
  int row = blockIdx.x * 4 + (threadIdx.x >> 6), lane = threadIdx.x & 63;
  if (row >= ns) return;
  uint4 w = *(const uint4*)(xW + (size_t)row * 256 + lane * 4);
  float x0 = dec_w(w.x), x1 = dec_w(w.y), x2 = dec_w(w.z), x3 = dec_w(w.w);
  float4 s4 = *(const float4*)(wsv + lane * 4);
  float vs = x0 * s4.x + x1 * s4.y + x2 * s4.z + x3 * s4.w;
  bool both = row < nd;
  float vd = 0.f;
  if (both){
    float4 d4 = *(const float4*)(wdv + lane * 4);
    vd = x0 * d4.x + x1 * d4.y + x2 * d4.z + x3 * d4.w;
  }
  #pragma unroll
  for (int off2 = 32; off2; off2 >>= 1){
    vs += __shfl_down(vs, off2);
    vd += __shfl_down(vd, off2);
  }
  if (!lane){
    as_out[row] = vs;
    if (both) ad_out[row] = vd;
  }
}

// ---------- edges + self-loops: leaky-relu alpha -> e=exp(alpha) directly, degree ----
// NO-MAX softmax (round-12, exact up to fp noise: alphas O(1), softmax shift-invariant)
__global__ __launch_bounds__(256) void edge_a(const int* __restrict__ src,
    const int* __restrict__ dst, const float* __restrict__ as_, const float* __restrict__ ad_,
    float* __restrict__ e_edge, float* __restrict__ e_self,
    int* __restrict__ cnt, int E, int nd){
  int i = blockIdx.x * 256 + threadIdx.x;
  if (i < E){
    int s = src[i], d = dst[i];
    float al = as_[s] + ad_[d];
    al = al > 0.f ? al : NEG_SLOPE * al;
    e_edge[i] = expf(al);
    atomicAdd(&cnt[d], 1);
  } else if (i < E + nd){
    int j = i - E;
    float al = as_[j] + ad_[j];
    al = al > 0.f ? al : NEG_SLOPE * al;
    e_self[j] = expf(al);
  }
}

// ---------- scan, 2 dispatches ----------
__global__ __launch_bounds__(256) void scan_part(const int* __restrict__ cnt,
    int* __restrict__ part, int n){
  __shared__ int ws_[4];
  int lane = threadIdx.x & 63, wv = threadIdx.x >> 6;
  int i = blockIdx.x * 256 + threadIdx.x;
  int v = (i < n) ? cnt[i] : 0;
  #pragma unroll
  for (int off = 32; off; off >>= 1) v += __shfl_down(v, off);
  if (!lane) ws_[wv] = v;
  __syncthreads();
  if (!threadIdx.x) part[blockIdx.x] = ws_[0] + ws_[1] + ws_[2] + ws_[3];
}
__global__ __launch_bounds__(256) void scan_fin(const int* __restrict__ cnt,
    const int* __restrict__ part, int* __restrict__ base, int* __restrict__ cursor,
    int n, int nb){
  __shared__ int ps[128];
  __shared__ int wtot[4];
  int t = threadIdx.x;
  if (t < 128) ps[t] = (t < nb) ? part[t] : 0;
  __syncthreads();
  #pragma unroll
  for (int off = 1; off < 128; off <<= 1){
    int v = (t < 128 && t >= off) ? ps[t - off] : 0;
    __syncthreads();
    if (t < 128) ps[t] += v;
    __syncthreads();
  }
  int lane = t & 63, wv = t >> 6;
  int i = blockIdx.x * 256 + t;
  int v = (i < n) ? cnt[i] : 0;
  int incl = v;
  #pragma unroll
  for (int off = 1; off < 64; off <<= 1){
    int s = __shfl_up(incl, off);
    if (lane >= off) incl += s;
  }
  if (lane == 63) wtot[wv] = incl;
  __syncthreads();
  int woff = blockIdx.x ? ps[blockIdx.x - 1] : 0;
  for (int w = 0; w < wv; w++) woff += wtot[w];
  int excl = woff + incl - v;
  if (i < n){ base[i] = excl; cursor[i] = excl; }
}

// ---------- CSR fill (e already computed in edge_a) ----------
__global__ __launch_bounds__(256) void edge_b(const int* __restrict__ src,
    const int* __restrict__ dst, const float* __restrict__ e_edge,
    int* __restrict__ cursor, int* __restrict__ csr_src, float* __restrict__ csr_e, int E){
  int e = blockIdx.x * 256 + threadIdx.x;
  if (e >= E) return;
  int d = dst[e];
  int pos = atomicAdd(&cursor[d], 1);
  csr_src[pos] = src[e];
  csr_e[pos] = e_edge[e];
}

// ---------- gather: agg[j] = (sum_e w_e x[src] + w_self x[j]) / sum w ----------
// x from LINEAR interleaved u32 rows (1KB contiguous per edge, coalesced uint4/lane)
// with 8-deep independent-load unroll (MLP). Output packed (GEMM A-operand).
__global__ __launch_bounds__(256) void gather_agg(const unsigned* __restrict__ xW,
    const int* __restrict__ base, const int* __restrict__ cnt,
    const int* __restrict__ csr_src, const float* __restrict__ csr_e,
    const float* __restrict__ e_self,
    u16* __restrict__ aggH, u16* __restrict__ aggL, int n){
  int wv = threadIdx.x >> 6, lane = threadIdx.x & 63;
  int j = blockIdx.x * 4 + wv;
  if (j >= n) return;
  int b0 = base[j], cn = cnt[j];
  float a0 = 0.f, a1 = 0.f, a2 = 0.f, a3 = 0.f, ds = 0.f;
  int k = 0;
  for (; k + 8 <= cn; k += 8){
    int ss[8]; float ee[8]; uint4 ww[8];
    #pragma unroll
    for (int u = 0; u < 8; u++){ ss[u] = csr_src[b0 + k + u]; ee[u] = csr_e[b0 + k + u]; }
    #pragma unroll
    for (int u = 0; u < 8; u++) ww[u] = *(const uint4*)(xW + (size_t)ss[u] * 256 + lane * 4);
    #pragma unroll
    for (int u = 0; u < 8; u++){
      float e = ee[u];
      a0 += e * dec_w(ww[u].x); a1 += e * dec_w(ww[u].y);
      a2 += e * dec_w(ww[u].z); a3 += e * dec_w(ww[u].w);
      ds += e;
    }
  }
  for (; k < cn; k++){
    int s = csr_src[b0 + k];
    float e = csr_e[b0 + k];
    uint4 w = *(const uint4*)(xW + (size_t)s * 256 + lane * 4);
    a0 += e * dec_w(w.x); a1 += e * dec_w(w.y);
    a2 += e * dec_w(w.z); a3 += e * dec_w(w.w);
    ds += e;
  }
  float es = e_self[j];
  {
    uint4 w = *(const uint4*)(xW + (size_t)j * 256 + lane * 4);
    a0 += es * dec_w(w.x); a1 += es * dec_w(w.y);
    a2 += es * dec_w(w.z); a3 += es * dec_w(w.w);
    ds += es;
  }
  float inv = 1.f / ds;
  ushort4 H4, L4;
  f2hilo(a0 * inv, H4.x, L4.x); f2hilo(a1 * inv, H4.y, L4.y);
  f2hilo(a2 * inv, H4.z, L4.z); f2hilo(a3 * inv, H4.w, L4.w);
  size_t off = pk_off(j, lane * 4, 8);
  *(ushort4*)(aggH + off) = H4;
  *(ushort4*)(aggL + off) = L4;
}

extern "C" void kernel_launch(void* const* d_in, const int* in_sizes, int n_in,
                              void* d_out, int out_size, void* d_ws, size_t ws_size,
                              hipStream_t stream){
  const float* feats   = (const float*)d_in[0];
  const float* Win     = (const float*)d_in[1];
  const float* b_in    = (const float*)d_in[2];
  const float* Wsrc    = (const float*)d_in[3];
  const float* Wdst    = (const float*)d_in[4];
  const float* att_src = (const float*)d_in[5];
  const float* att_dst = (const float*)d_in[6];
  const float* gat_b   = (const float*)d_in[7];
  const float* W_ih    = (const float*)d_in[8];
  const float* W_hh    = (const float*)d_in[9];
  const float* Wout    = (const float*)d_in[10];
  const float* b_out   = (const float*)d_in[11];
  const int* srcs[3] = {(const int*)d_in[12], (const int*)d_in[14], (const int*)d_in[16]};
  const int* dsts[3] = {(const int*)d_in[13], (const int*)d_in[15], (const int*)d_in[17]};
  (void)in_sizes; (void)n_in; (void)out_size; (void)ws_size;

  const int ns_a[3] = {60000, 30000, 15000};
  const int nd_a[3] = {30000, 15000, 7500};
  const int E_a[3]  = {480000, 240000, 120000};

  // ---- workspace layout (~231 MiB), aliasing lifetime-checked ----
  char* w = (char*)d_ws;
  unsigned* xW = (unsigned*)(w + 0);              // linear interleaved x rows, 60032x256 u32
  u16* featsH  = (u16*)(w + 61500000);            // packed 60032x128; dead after inproj
  u16* featsL  = (u16*)(w + 77000000);
  float* c     = (float*)(w + 61500000);          // [30000][256] f32; alias feats
                                                  // (feats dead after inproj; c first written hop0 gates)
  u16* aggH    = (u16*)(w + 92500000);            // packed 30080x256
  u16* aggL    = (u16*)(w + 108000000);
  u16* hAH     = (u16*)(w + 123500000);           // packed h ping-pong A
  u16* hAL     = (u16*)(w + 139000000);
  u16* hBH     = (u16*)(w + 154500000);           // set B
  u16* hBL     = (u16*)(w + 170000000);
  u16* xbH     = (u16*)(w + 185500000);
  u16* xbL     = (u16*)(w + 201000000);
  u16* WinH = (u16*)(w + 216500000);  u16* WinL = WinH + 32768;
  u16* WsH  = WinL + 32768;           u16* WsL  = WsH + 196608;
  u16* IhH  = WsL + 196608;           u16* IhL  = IhH + 786432;
  u16* HhH  = IhL + 786432;           u16* HhL  = HhH + 786432;
  u16* WoH  = HhL + 786432;           u16* WoL  = WoH + 32768;
  float* wsv = (float*)(w + 224200000); float* wdv = wsv + 768;
  float* alpha_s = wdv + 768;
  float* alpha_d = alpha_s + 60000;
  float* e_edge  = alpha_d + 30000;               // per-edge exp(alpha)
  float* e_self  = e_edge + 480000;               // per-node self exp(alpha)
  int* cnt       = (int*)(e_self + 30000);
  int* base      = cnt + 30000;
  int* cursor    = base + 30000;
  int* part      = cursor + 30000;                // scan partials (<=128)
  int* csr_src   = part + 256;
  float* csr_e   = (float*)(csr_src + 480000);

  // ---- one-time prep (inputs only) ----
  prep_w<<<7168, 256, 0, stream>>>(Win, Wsrc, W_ih, W_hh, Wout,
      WinH, WinL, WsH, WsL, IhH, IhL, HhH, HhL, WoH, WoL);
  prep_wvec<<<384, 256, 0, stream>>>(Wsrc, Wdst, att_src, att_dst, wsv, wdv);
  cvt_feats<<<7500, 256, 0, stream>>>(feats, featsH, featsL, 60000);

  // ---- input projection: x0 (linear interleaved) = feats @ Win + b_in ----
  {
    dim3 g(PAD8(CDIV(60000, 128)), 2);
    mfma_gemm<<<g, 256, 0, stream>>>(featsH, featsL, WinH, WinL,
        nullptr, nullptr, nullptr, nullptr, 1, 60000, 256, 128,
        b_in, nullptr, nullptr, nullptr, xW, nullptr, nullptr,
        nullptr, nullptr, nullptr, 0, 0);
  }

  u16* hCurH = hAH; u16* hCurL = hAL;   // packed h from previous hop (pair-1 A-op)
  for (int hop = 0; hop < 3; hop++){
    const int ns = ns_a[hop], nd = nd_a[hop], E = E_a[hop];
    const int nb = CDIV(nd, 256);
    hipMemsetAsync(cnt, 0, (size_t)nd * 4, stream);

    alpha_mv<<<CDIV(ns, 4), 256, 0, stream>>>(xW, wsv + hop * 256, wdv + hop * 256,
        alpha_s, alpha_d, ns, nd);
    edge_a<<<CDIV(E + nd, 256), 256, 0, stream>>>(srcs[hop], dsts[hop], alpha_s, alpha_d,
        e_edge, e_self, cnt, E, nd);
    scan_part<<<nb, 256, 0, stream>>>(cnt, part, nd);
    scan_fin<<<nb, 256, 0, stream>>>(cnt, part, base, cursor, nd, nb);
    edge_b<<<CDIV(E, 256), 256, 0, stream>>>(srcs[hop], dsts[hop], e_edge,
        cursor, csr_src, csr_e, E);
    gather_agg<<<CDIV(nd, 4), 256, 0, stream>>>(xW, base, cnt, csr_src, csr_e,
        e_self, aggH, aggL, nd);

    // xb(packed) = tanh(agg @ WsrcT + gat_b)   [M = nd rows]
    {
      dim3 g(PAD8(CDIV(nd, 128)), 2);
      mfma_gemm<<<g, 256, 0, stream>>>(aggH, aggL, WsH + (size_t)hop * 65536, WsL + (size_t)hop * 65536,
          nullptr, nullptr, nullptr, nullptr, 1, nd, 256, 256,
          gat_b + hop * 256, nullptr, xbH, xbL, nullptr, nullptr, nullptr,
          nullptr, nullptr, nullptr, 0, 1);
    }

    // gates GEMM + fused LSTM; h: packed ping-pong (A-op) + linear xW (next hop's
    // gather/alpha; dead after hop 1 -> skip at hop 2)
    u16* hNewH = (hop == 0) ? hAH : (hCurH == hAH ? hBH : hAH);
    u16* hNewL = (hop == 0) ? hAL : (hCurL == hAL ? hBL : hAL);
    {
      dim3 g(PAD8(CDIV(nd, 128)), 8);
      mfma_gemm<<<g, 256, 0, stream>>>(xbH, xbL, IhH + (size_t)hop * 262144, IhL + (size_t)hop * 262144,
          hCurH, hCurL, HhH + (size_t)hop * 262144, HhL + (size_t)hop * 262144,
          hop ? 2 : 1, nd, 1024, 256,
          nullptr, nullptr, nullptr, nullptr, nullptr,
          c, c, hNewH, hNewL, hop < 2 ? xW : nullptr, hop == 0 ? 1 : 0, 0);
    }
    hCurH = hNewH; hCurL = hNewL;
  }

  // ---- output projection (N=128): d_out = h @ Wout + b_out ----
  {
    dim3 g(PAD8(CDIV(7500, 128)), 1);
    mfma_gemm<<<g, 256, 0, stream>>>(hCurH, hCurL, WoH, WoL,
        nullptr, nullptr, nullptr, nullptr, 1, 7500, 128, 256,
        b_out, (float*)d_out, nullptr, nullptr, nullptr, nullptr, nullptr,
        nullptr, nullptr, nullptr, 0, 0);
  }
}

// Round 16
// 567.595 us; speedup vs baseline: 1.2244x; 1.0739x over previous
//
#include <hip/hip_runtime.h>
#include <cstddef>
#include <cstdint>

#define CDIV(a,b) (((a)+(b)-1)/(b))
#define PAD8(x) ((((x)+7)/8)*8)
#define NEG_SLOPE 0.2f

typedef unsigned short u16;
typedef __attribute__((ext_vector_type(8))) short bf16x8;
typedef __attribute__((ext_vector_type(4))) float f32x4;

// ---------- bf16 helpers (explicit RNE, hi/lo split: v ~= hi + lo, ~17 mantissa bits) ----------
__device__ __forceinline__ u16 bf16_rne(float v){
  unsigned u = __float_as_uint(v);
  unsigned r = (u + 0x7FFFu + ((u >> 16) & 1u)) >> 16;
  return (u16)r;
}
__device__ __forceinline__ float bf16_to_f(u16 h){
  return __uint_as_float(((unsigned)h) << 16);
}
__device__ __forceinline__ void f2hilo(float v, u16& h, u16& l){
  h = bf16_rne(v);
  float r = v - bf16_to_f(h);
  l = bf16_rne(r);
}
// interleaved word: (hi<<16)|lo ; value = asfloat(w&0xFFFF0000) + asfloat(w<<16)
__device__ __forceinline__ float dec_w(unsigned w){
  return __uint_as_float(w & 0xFFFF0000u) + __uint_as_float(w << 16);
}

// ---------- tile-packed operand layout (round-8, verified; GEMM A/B operands only) ----
// Matrix [rows][K] stored as bricks: 128-row block r0, k-tile t (BK=32) -> contiguous
// 4096 u16 (8KB). Element (rr,k) at phys chunk (s+(rr>>1))&3 (s=(k&31)>>3): LDS bank
// swizzle PRE-BAKED, GEMM staging is a pure linear 8KB copy (ideal DRAM bursts).
__device__ __forceinline__ size_t pk_off(int row, int k, int nbk){
  int r0 = row >> 7, rr = row & 127;
  int t = k >> 5, kk = k & 31;
  int s = kk >> 3, w = kk & 7;
  int phys = (s + (rr >> 1)) & 3;
  return ((size_t)(r0 * nbk + t) * 128 + rr) * 32 + phys * 8 + w;
}

__device__ __forceinline__ float sigmf(float x){ return 1.f / (1.f + expf(-x)); }

// ---------- async global->LDS, 16B per lane ----------
__device__ __forceinline__ void gload16(const void* g, void* l){
  __builtin_amdgcn_global_load_lds((const __attribute__((address_space(1))) void*)g,
                                   (__attribute__((address_space(3))) void*)l, 16, 0, 0);
}

// =====================================================================================
// Fused MFMA GEMM — SINGLE untemplated instantiation (r15's proven build discipline),
// now 2-PHASE numerics everywhere: C = sum_pairs (Ah + Al) @ Bh^T.
//   Activations keep hi/lo bf16 (~17-bit); weights bf16-only. Round-13 measured
//   absmax UNCHANGED (1.2e-4) with gates+xb 2-phase — weight-lo is below the
//   activation hi/lo error floor. Extending to inproj/outproj predicted <=3e-4
//   vs 7.4e-4 threshold.
// 128x128 tile, 4 waves, BK=32, double-buffered LDS (2 x 24KB = 48KB -> 3 blocks/CU),
// counted vmcnt(6) depth-2 prefetch, 32 MFMA per 2-barrier window.
// Operands tile-packed (pk_off): stage = linear 8KB copies. Grid (m-blocks %8 padded,
// n-blocks): column-siblings share an XCD -> A fetched ~once per XCD L2.
// NOTE (rounds 7+11): 256^2 tile at 1 block/CU regresses (lockstep waves expose every
// barrier stall). Do not retry without the full 8-phase fine interleave.
// NOTE (rounds 13-15): a second GEMM instantiation in the TU cost ~30-40us on the
// other variant's dispatches — keep exactly ONE GEMM kernel.
// Epilogues: (a) f32 C (+bias), (b) packed hi/lo and/or LINEAR u32 interleaved
// (+bias, optional tanh), (c) fused LSTM (gate-interleaved B; writes c f32 +
// packed h hi/lo + linear u32 h for the next hop's gather/alpha).
// =====================================================================================
__global__ __launch_bounds__(256, 2) void mfma_gemm(
    const u16* __restrict__ Ah0, const u16* __restrict__ Al0,
    const u16* __restrict__ Bh0,
    const u16* __restrict__ Ah1, const u16* __restrict__ Al1,
    const u16* __restrict__ Bh1,
    int npairs, int M, int N, int K,
    const float* __restrict__ bias, float* __restrict__ Cf,
    u16* __restrict__ outHi, u16* __restrict__ outLo, unsigned* __restrict__ outW,
    const float* __restrict__ cIn, float* __restrict__ cOut,
    u16* __restrict__ hH, u16* __restrict__ hL, unsigned* __restrict__ hW,
    int lstm_first, int tanh_out)
{
  if ((int)(blockIdx.x * 128) >= M) return;   // pad-%8 guard (block-uniform)
  __shared__ u16 smem[2 * 12288];  // per buf: Ah@0 Al@4096 Bh@8192 (u16 units)
  const int tid = threadIdx.x;
  const int lane = tid & 63, wv = tid >> 6;
  const int l15 = lane & 15, lq = lane >> 4;
  const int wr = wv >> 1, wc = wv & 1;
  const int bm = blockIdx.x * 128, bn = blockIdx.y * 128;
  const int nbk = K >> 5, NT = npairs * nbk;
  const size_t Abase = (size_t)(bm >> 7) * nbk * 4096;
  const size_t Bbase = (size_t)(bn >> 7) * nbk * 4096;

  f32x4 acc[4][4];
  #pragma unroll
  for (int m = 0; m < 4; m++)
    #pragma unroll
    for (int n = 0; n < 4; n++) acc[m][n] = (f32x4){0.f, 0.f, 0.f, 0.f};

  // staging: thread's chunk c = i*256+tid -> linear 16B at brick offset c*16
  size_t goff[2]; int ldso2[2];
  #pragma unroll
  for (int i = 0; i < 2; i++){
    goff[i]  = (size_t)(i * 256 + tid) * 8;        // u16 units, contiguous
    ldso2[i] = (i * 256 + (tid & 192)) * 8;        // wave-uniform LDS base
  }

  // fragment read offsets (u16 units within a buffer); phys chunk = (lq + (r>>1)) & 3
  int aoff[4], boff[4];
  #pragma unroll
  for (int m = 0; m < 4; m++){
    int r = wr * 64 + m * 16 + l15;
    aoff[m] = r * 32 + ((lq + (r >> 1)) & 3) * 8;
  }
  #pragma unroll
  for (int n = 0; n < 4; n++){
    int r = wc * 64 + n * 16 + l15;
    boff[n] = r * 32 + ((lq + (r >> 1)) & 3) * 8;
  }

  auto stage = [&](int buf, int t){
    int q = (npairs > 1 && t >= nbk) ? 1 : 0;
    const u16* A_h = q ? Ah1 : Ah0;  const u16* A_l = q ? Al1 : Al0;
    const u16* B_h = q ? Bh1 : Bh0;
    int tl = q ? t - nbk : t;
    size_t ab = Abase + (size_t)tl * 4096;
    size_t bb = Bbase + (size_t)tl * 4096;
    u16* sb = smem + buf * 12288;
    #pragma unroll
    for (int i = 0; i < 2; i++){
      gload16(A_h + ab + goff[i], sb + ldso2[i]);
      gload16(A_l + ab + goff[i], sb + 4096 + ldso2[i]);
      gload16(B_h + bb + goff[i], sb + 8192 + ldso2[i]);
    }
  };

  stage(0, 0);                  // 6 loads/wave outstanding
  int cur = 0;
  #pragma unroll 1
  for (int t = 0; t < NT; t++){
    if (t + 1 < NT){
      stage(cur ^ 1, t + 1);    // +6 -> up to 12 outstanding
      asm volatile("s_waitcnt vmcnt(6)" ::: "memory");   // tile-t landed; t+1 in flight
    } else {
      asm volatile("s_waitcnt vmcnt(0)" ::: "memory");
    }
    __builtin_amdgcn_sched_barrier(0);
    __builtin_amdgcn_s_barrier();        // tile-t visible to all waves
    __builtin_amdgcn_sched_barrier(0);
    const u16* sb = smem + cur * 12288;
    bf16x8 ah[4], al[4], bh[4];
    #pragma unroll
    for (int m = 0; m < 4; m++){
      ah[m] = *(const bf16x8*)(sb + aoff[m]);
      al[m] = *(const bf16x8*)(sb + 4096 + aoff[m]);
    }
    #pragma unroll
    for (int n = 0; n < 4; n++){
      bh[n] = *(const bf16x8*)(sb + 8192 + boff[n]);
    }
    #pragma unroll
    for (int m = 0; m < 4; m++)
      #pragma unroll
      for (int n = 0; n < 4; n++){
        acc[m][n] = __builtin_amdgcn_mfma_f32_16x16x32_bf16(ah[m], bh[n], acc[m][n], 0, 0, 0);
        acc[m][n] = __builtin_amdgcn_mfma_f32_16x16x32_bf16(al[m], bh[n], acc[m][n], 0, 0, 0);
      }
    __builtin_amdgcn_sched_barrier(0);
    __builtin_amdgcn_s_barrier();        // buf[cur] released; NO vmcnt drain
    cur ^= 1;
  }

  // epilogue: C/D layout col=lane&15, row=(lane>>4)*4+j (m89/m91-verified)
  const int rb = bm + wr * 64 + lq * 4;
  if (cOut){
    // LSTM mode: lane owns channel ch; n-frag index == gate (i,f,g,o)
    const int ch = (bn >> 2) + wc * 16 + l15;
    #pragma unroll
    for (int m = 0; m < 4; m++){
      #pragma unroll
      for (int j = 0; j < 4; j++){
        int row = rb + m * 16 + j;
        if (row >= M) continue;
        float i_ = acc[m][0][j], f_ = acc[m][1][j], g_ = acc[m][2][j], o_ = acc[m][3][j];
        float si = sigmf(i_), tg = tanhf(g_), so = sigmf(o_);
        size_t loff = (size_t)row * 256 + ch;
        float cn = lstm_first ? si * tg : sigmf(f_) * cIn[loff] + si * tg;
        float hn = so * tanhf(cn);
        cOut[loff] = cn;
        u16 hh, hl; f2hilo(hn, hh, hl);
        size_t pko = pk_off(row, ch, 8);
        hH[pko] = hh; hL[pko] = hl;
        if (hW) hW[loff] = ((unsigned)hh << 16) | (unsigned)hl;   // linear copy
      }
    }
  } else {
    const int cb = bn + wc * 64 + l15;
    #pragma unroll
    for (int n = 0; n < 4; n++){
      int col = cb + n * 16;
      float bv = bias ? bias[col] : 0.f;
      #pragma unroll
      for (int m = 0; m < 4; m++){
        #pragma unroll
        for (int j = 0; j < 4; j++){
          int row = rb + m * 16 + j;
          if (row >= M) continue;
          float v = acc[m][n][j] + bv;
          if (tanh_out) v = tanhf(v);
          if (Cf) Cf[(size_t)row * N + col] = v;
          if (outHi || outW){
            u16 hh, hl; f2hilo(v, hh, hl);
            if (outHi){
              size_t pko = pk_off(row, col, 8);
              outHi[pko] = hh; outLo[pko] = hl;
            }
            if (outW) outW[(size_t)row * 256 + col] = ((unsigned)hh << 16) | (unsigned)hl;
          }
        }
      }
    }
  }
}

// ---------- feats f32 [60000][128] -> packed hi/lo bf16 (nbk=4), 4 elems/thread ----------
__global__ __launch_bounds__(256) void cvt_feats(const float* __restrict__ in,
    u16* __restrict__ hi, u16* __restrict__ lo, int nrow){
  int i = blockIdx.x * 256 + threadIdx.x;       // quad index
  int row = i >> 5, k4 = (i & 31) * 4;
  if (row >= nrow) return;
  float4 v = *(const float4*)(in + (size_t)row * 128 + k4);
  ushort4 h4, l4;
  f2hilo(v.x, h4.x, l4.x); f2hilo(v.y, h4.y, l4.y);
  f2hilo(v.z, h4.z, l4.z); f2hilo(v.w, h4.w, l4.w);
  size_t off = pk_off(row, k4, 4);              // w in {0,4}: ushort4 stays in-chunk
  *(ushort4*)(hi + off) = h4;
  *(ushort4*)(lo + off) = l4;
}

// ---------- one-shot weight prep: transpose/permute + PACKED bf16 (hi only needed
// by the 2-phase GEMM; lo halves no longer written). Reads coalesced over n.
// W_ih/W_hh rows PERMUTED to gate-interleaved layout: orig row (gate*256+ch)
// -> n' = (ch>>4)*64 + gate*16 + (ch&15), so the GEMM epilogue can fuse LSTM.
__global__ __launch_bounds__(256) void prep_w(const float* __restrict__ Win,
    const float* __restrict__ Wsrc, const float* __restrict__ Wih,
    const float* __restrict__ Whh, const float* __restrict__ Wout,
    u16* WinH, u16* WsH, u16* IhH, u16* HhH, u16* WoH){
  int idx = blockIdx.x * 256 + threadIdx.x;
  float v; u16 *ph; size_t off;
  if (idx < 32768){                       // WinT [256][128] <- Win[128][256]; nbk=4
    int n = idx & 255, k = idx >> 8;
    v = Win[k * 256 + n]; ph = WinH; off = pk_off(n, k, 4);
  } else if (idx < 229376){               // WsT [3][256][256] <- Wsrc^T; nbk=8
    int t = idx - 32768; int hop = t >> 16, r = t & 65535, n = r & 255, k = r >> 8;
    v = Wsrc[hop * 65536 + k * 256 + n]; ph = WsH;
    off = (size_t)hop * 65536 + pk_off(n, k, 8);
  } else if (idx < 1015808){              // W_ih [3][1024][256], gate-interleaved; nbk=8
    int t = idx - 229376;
    int hop = t >> 18, r = (t >> 8) & 1023, k = t & 255;
    int gate = r >> 8, ch = r & 255;
    int np = ((ch >> 4) << 6) + (gate << 4) + (ch & 15);
    v = Wih[t]; ph = IhH;
    off = (size_t)hop * 262144 + pk_off(np, k, 8);
  } else if (idx < 1802240){              // W_hh, same permutation
    int t = idx - 1015808;
    int hop = t >> 18, r = (t >> 8) & 1023, k = t & 255;
    int gate = r >> 8, ch = r & 255;
    int np = ((ch >> 4) << 6) + (gate << 4) + (ch & 15);
    v = Whh[t]; ph = HhH;
    off = (size_t)hop * 262144 + pk_off(np, k, 8);
  } else if (idx < 1835008){              // WoT [128][256] <- Wout^T; nbk=8
    int t = idx - 1802240; int n = t & 127, k = t >> 7;
    v = Wout[k * 128 + n]; ph = WoH; off = pk_off(n, k, 8);
  } else return;
  ph[off] = bf16_rne(v);
}

// ---------- w_s[hop] = Wsrc[hop]@a_s, w_d[hop] = Wdst[hop]@a_d (row dots, f32) ----------
__global__ __launch_bounds__(256) void prep_wvec(const float* __restrict__ Wsrc,
    const float* __restrict__ Wdst, const float* __restrict__ as_,
    const float* __restrict__ ad_, float* __restrict__ wsv, float* __restrict__ wdv){
  int wid = blockIdx.x * 4 + (threadIdx.x >> 6), lane = threadIdx.x & 63;
  if (wid >= 6 * 256) return;
  int vec = wid >> 8, i = wid & 255;
  int hop = vec >> 1; bool isd = vec & 1;
  const float* Wrow = (isd ? Wdst : Wsrc) + (size_t)hop * 65536 + (size_t)i * 256;
  const float* a = (isd ? ad_ : as_) + hop * 256;
  float4 w4 = *(const float4*)(Wrow + lane * 4);
  float4 a4 = *(const float4*)(a + lane * 4);
  float v = w4.x * a4.x + w4.y * a4.y + w4.z * a4.z + w4.w * a4.w;
  #pragma unroll
  for (int off = 32; off; off >>= 1) v += __shfl_down(v, off);
  if (!lane) (isd ? wdv : wsv)[hop * 256 + i] = v;
}

// ---------- alpha from LINEAR interleaved x: coalesced uint4 row reads ----------
// Rows < nd need BOTH the src-dot (vs wsv) and dst-dot (vs wdv): compute both in ONE
// row pass (saves re-reading those rows; ~13MB across hops).
__global__ __launch_bounds__(256) void alpha_mv(const unsigned* __restrict__ xW,
    const float* __restrict__ wsv, const float* __restrict__ wdv,
    float* __restrict__ as_out, float* __restrict__ ad_out, int ns, int nd){
  int row = blockIdx.x * 4 + (threadIdx.x >> 6), lane = threadIdx.x & 63;
  if (row >= ns) return;
  uint4 w = *(const uint4*)(xW + (size_t)row * 256 + lane * 4);
  float x0 = dec_w(w.x), x1 = dec_w(w.y), x2 = dec_w(w.z), x3 = dec_w(w.w);
  float4 s4 = *(const float4*)(wsv + lane * 4);
  float vs = x0 * s4.x + x1 * s4.y + x2 * s4.z + x3 * s4.w;
  bool both = row < nd;
  float vd = 0.f;
  if (both){
    float4 d4 = *(const float4*)(wdv + lane * 4);
    vd = x0 * d4.x + x1 * d4.y + x2 * d4.z + x3 * d4.w;
  }
  #pragma unroll
  for (int off2 = 32; off2; off2 >>= 1){
    vs += __shfl_down(vs, off2);
    vd += __shfl_down(vd, off2);
  }
  if (!lane){
    as_out[row] = vs;
    if (both) ad_out[row] = vd;
  }
}

// ---------- edges + self-loops: leaky-relu alpha -> e=exp(alpha) directly, degree ----
// NO-MAX softmax (round-12, exact up to fp noise: alphas O(1), softmax shift-invariant)
__global__ __launch_bounds__(256) void edge_a(const int* __restrict__ src,
    const int* __restrict__ dst, const float* __restrict__ as_, const float* __restrict__ ad_,
    float* __restrict__ e_edge, float* __restrict__ e_self,
    int* __restrict__ cnt, int E, int nd){
  int i = blockIdx.x * 256 + threadIdx.x;
  if (i < E){
    int s = src[i], d = dst[i];
    float al = as_[s] + ad_[d];
    al = al > 0.f ? al : NEG_SLOPE * al;
    e_edge[i] = expf(al);
    atomicAdd(&cnt[d], 1);
  } else if (i < E + nd){
    int j = i - E;
    float al = as_[j] + ad_[j];
    al = al > 0.f ? al : NEG_SLOPE * al;
    e_self[j] = expf(al);
  }
}

// ---------- scan, 2 dispatches ----------
__global__ __launch_bounds__(256) void scan_part(const int* __restrict__ cnt,
    int* __restrict__ part, int n){
  __shared__ int ws_[4];
  int lane = threadIdx.x & 63, wv = threadIdx.x >> 6;
  int i = blockIdx.x * 256 + threadIdx.x;
  int v = (i < n) ? cnt[i] : 0;
  #pragma unroll
  for (int off = 32; off; off >>= 1) v += __shfl_down(v, off);
  if (!lane) ws_[wv] = v;
  __syncthreads();
  if (!threadIdx.x) part[blockIdx.x] = ws_[0] + ws_[1] + ws_[2] + ws_[3];
}
__global__ __launch_bounds__(256) void scan_fin(const int* __restrict__ cnt,
    const int* __restrict__ part, int* __restrict__ base, int* __restrict__ cursor,
    int n, int nb){
  __shared__ int ps[128];
  __shared__ int wtot[4];
  int t = threadIdx.x;
  if (t < 128) ps[t] = (t < nb) ? part[t] : 0;
  __syncthreads();
  #pragma unroll
  for (int off = 1; off < 128; off <<= 1){
    int v = (t < 128 && t >= off) ? ps[t - off] : 0;
    __syncthreads();
    if (t < 128) ps[t] += v;
    __syncthreads();
  }
  int lane = t & 63, wv = t >> 6;
  int i = blockIdx.x * 256 + t;
  int v = (i < n) ? cnt[i] : 0;
  int incl = v;
  #pragma unroll
  for (int off = 1; off < 64; off <<= 1){
    int s = __shfl_up(incl, off);
    if (lane >= off) incl += s;
  }
  if (lane == 63) wtot[wv] = incl;
  __syncthreads();
  int woff = blockIdx.x ? ps[blockIdx.x - 1] : 0;
  for (int w = 0; w < wv; w++) woff += wtot[w];
  int excl = woff + incl - v;
  if (i < n){ base[i] = excl; cursor[i] = excl; }
}

// ---------- CSR fill (e already computed in edge_a) ----------
__global__ __launch_bounds__(256) void edge_b(const int* __restrict__ src,
    const int* __restrict__ dst, const float* __restrict__ e_edge,
    int* __restrict__ cursor, int* __restrict__ csr_src, float* __restrict__ csr_e, int E){
  int e = blockIdx.x * 256 + threadIdx.x;
  if (e >= E) return;
  int d = dst[e];
  int pos = atomicAdd(&cursor[d], 1);
  csr_src[pos] = src[e];
  csr_e[pos] = e_edge[e];
}

// ---------- gather: agg[j] = (sum_e w_e x[src] + w_self x[j]) / sum w ----------
// x from LINEAR interleaved u32 rows (1KB contiguous per edge, coalesced uint4/lane)
// with 8-deep independent-load unroll (MLP). Output packed (GEMM A-operand).
__global__ __launch_bounds__(256) void gather_agg(const unsigned* __restrict__ xW,
    const int* __restrict__ base, const int* __restrict__ cnt,
    const int* __restrict__ csr_src, const float* __restrict__ csr_e,
    const float* __restrict__ e_self,
    u16* __restrict__ aggH, u16* __restrict__ aggL, int n){
  int wv = threadIdx.x >> 6, lane = threadIdx.x & 63;
  int j = blockIdx.x * 4 + wv;
  if (j >= n) return;
  int b0 = base[j], cn = cnt[j];
  float a0 = 0.f, a1 = 0.f, a2 = 0.f, a3 = 0.f, ds = 0.f;
  int k = 0;
  for (; k + 8 <= cn; k += 8){
    int ss[8]; float ee[8]; uint4 ww[8];
    #pragma unroll
    for (int u = 0; u < 8; u++){ ss[u] = csr_src[b0 + k + u]; ee[u] = csr_e[b0 + k + u]; }
    #pragma unroll
    for (int u = 0; u < 8; u++) ww[u] = *(const uint4*)(xW + (size_t)ss[u] * 256 + lane * 4);
    #pragma unroll
    for (int u = 0; u < 8; u++){
      float e = ee[u];
      a0 += e * dec_w(ww[u].x); a1 += e * dec_w(ww[u].y);
      a2 += e * dec_w(ww[u].z); a3 += e * dec_w(ww[u].w);
      ds += e;
    }
  }
  for (; k < cn; k++){
    int s = csr_src[b0 + k];
    float e = csr_e[b0 + k];
    uint4 w = *(const uint4*)(xW + (size_t)s * 256 + lane * 4);
    a0 += e * dec_w(w.x); a1 += e * dec_w(w.y);
    a2 += e * dec_w(w.z); a3 += e * dec_w(w.w);
    ds += e;
  }
  float es = e_self[j];
  {
    uint4 w = *(const uint4*)(xW + (size_t)j * 256 + lane * 4);
    a0 += es * dec_w(w.x); a1 += es * dec_w(w.y);
    a2 += es * dec_w(w.z); a3 += es * dec_w(w.w);
    ds += es;
  }
  float inv = 1.f / ds;
  ushort4 H4, L4;
  f2hilo(a0 * inv, H4.x, L4.x); f2hilo(a1 * inv, H4.y, L4.y);
  f2hilo(a2 * inv, H4.z, L4.z); f2hilo(a3 * inv, H4.w, L4.w);
  size_t off = pk_off(j, lane * 4, 8);
  *(ushort4*)(aggH + off) = H4;
  *(ushort4*)(aggL + off) = L4;
}

extern "C" void kernel_launch(void* const* d_in, const int* in_sizes, int n_in,
                              void* d_out, int out_size, void* d_ws, size_t ws_size,
                              hipStream_t stream){
  const float* feats   = (const float*)d_in[0];
  const float* Win     = (const float*)d_in[1];
  const float* b_in    = (const float*)d_in[2];
  const float* Wsrc    = (const float*)d_in[3];
  const float* Wdst    = (const float*)d_in[4];
  const float* att_src = (const float*)d_in[5];
  const float* att_dst = (const float*)d_in[6];
  const float* gat_b   = (const float*)d_in[7];
  const float* W_ih    = (const float*)d_in[8];
  const float* W_hh    = (const float*)d_in[9];
  const float* Wout    = (const float*)d_in[10];
  const float* b_out   = (const float*)d_in[11];
  const int* srcs[3] = {(const int*)d_in[12], (const int*)d_in[14], (const int*)d_in[16]};
  const int* dsts[3] = {(const int*)d_in[13], (const int*)d_in[15], (const int*)d_in[17]};
  (void)in_sizes; (void)n_in; (void)out_size; (void)ws_size;

  const int ns_a[3] = {60000, 30000, 15000};
  const int nd_a[3] = {30000, 15000, 7500};
  const int E_a[3]  = {480000, 240000, 120000};

  // ---- workspace layout (~231 MiB), aliasing lifetime-checked ----
  char* w = (char*)d_ws;
  unsigned* xW = (unsigned*)(w + 0);              // linear interleaved x rows, 60032x256 u32
  u16* featsH  = (u16*)(w + 61500000);            // packed 60032x128; dead after inproj
  u16* featsL  = (u16*)(w + 77000000);
  float* c     = (float*)(w + 61500000);          // [30000][256] f32; alias feats
                                                  // (feats dead after inproj; c first written hop0 gates)
  u16* aggH    = (u16*)(w + 92500000);            // packed 30080x256
  u16* aggL    = (u16*)(w + 108000000);
  u16* hAH     = (u16*)(w + 123500000);           // packed h ping-pong A
  u16* hAL     = (u16*)(w + 139000000);
  u16* hBH     = (u16*)(w + 154500000);           // set B
  u16* hBL     = (u16*)(w + 170000000);
  u16* xbH     = (u16*)(w + 185500000);
  u16* xbL     = (u16*)(w + 201000000);
  u16* WinH = (u16*)(w + 216500000);              // weight hi-only (2-phase GEMM)
  u16* WsH  = WinH + 32768;
  u16* IhH  = WsH + 196608;
  u16* HhH  = IhH + 786432;
  u16* WoH  = HhH + 786432;
  float* wsv = (float*)(w + 224200000); float* wdv = wsv + 768;
  float* alpha_s = wdv + 768;
  float* alpha_d = alpha_s + 60000;
  float* e_edge  = alpha_d + 30000;               // per-edge exp(alpha)
  float* e_self  = e_edge + 480000;               // per-node self exp(alpha)
  int* cnt       = (int*)(e_self + 30000);
  int* base      = cnt + 30000;
  int* cursor    = base + 30000;
  int* part      = cursor + 30000;                // scan partials (<=128)
  int* csr_src   = part + 256;
  float* csr_e   = (float*)(csr_src + 480000);

  // ---- one-time prep (inputs only) ----
  prep_w<<<7168, 256, 0, stream>>>(Win, Wsrc, W_ih, W_hh, Wout,
      WinH, WsH, IhH, HhH, WoH);
  prep_wvec<<<384, 256, 0, stream>>>(Wsrc, Wdst, att_src, att_dst, wsv, wdv);
  cvt_feats<<<7500, 256, 0, stream>>>(feats, featsH, featsL, 60000);

  // ---- input projection: x0 (linear interleaved) = feats @ Win + b_in ----
  {
    dim3 g(PAD8(CDIV(60000, 128)), 2);
    mfma_gemm<<<g, 256, 0, stream>>>(featsH, featsL, WinH,
        nullptr, nullptr, nullptr, 1, 60000, 256, 128,
        b_in, nullptr, nullptr, nullptr, xW, nullptr, nullptr,
        nullptr, nullptr, nullptr, 0, 0);
  }

  u16* hCurH = hAH; u16* hCurL = hAL;   // packed h from previous hop (pair-1 A-op)
  for (int hop = 0; hop < 3; hop++){
    const int ns = ns_a[hop], nd = nd_a[hop], E = E_a[hop];
    const int nb = CDIV(nd, 256);
    hipMemsetAsync(cnt, 0, (size_t)nd * 4, stream);

    alpha_mv<<<CDIV(ns, 4), 256, 0, stream>>>(xW, wsv + hop * 256, wdv + hop * 256,
        alpha_s, alpha_d, ns, nd);
    edge_a<<<CDIV(E + nd, 256), 256, 0, stream>>>(srcs[hop], dsts[hop], alpha_s, alpha_d,
        e_edge, e_self, cnt, E, nd);
    scan_part<<<nb, 256, 0, stream>>>(cnt, part, nd);
    scan_fin<<<nb, 256, 0, stream>>>(cnt, part, base, cursor, nd, nb);
    edge_b<<<CDIV(E, 256), 256, 0, stream>>>(srcs[hop], dsts[hop], e_edge,
        cursor, csr_src, csr_e, E);
    gather_agg<<<CDIV(nd, 4), 256, 0, stream>>>(xW, base, cnt, csr_src, csr_e,
        e_self, aggH, aggL, nd);

    // xb(packed) = tanh(agg @ WsrcT + gat_b)   [M = nd rows]
    {
      dim3 g(PAD8(CDIV(nd, 128)), 2);
      mfma_gemm<<<g, 256, 0, stream>>>(aggH, aggL, WsH + (size_t)hop * 65536,
          nullptr, nullptr, nullptr, 1, nd, 256, 256,
          gat_b + hop * 256, nullptr, xbH, xbL, nullptr, nullptr, nullptr,
          nullptr, nullptr, nullptr, 0, 1);
    }

    // gates GEMM + fused LSTM; h: packed ping-pong (A-op) + linear xW (next hop's
    // gather/alpha; dead after hop 1 -> skip at hop 2)
    u16* hNewH = (hop == 0) ? hAH : (hCurH == hAH ? hBH : hAH);
    u16* hNewL = (hop == 0) ? hAL : (hCurL == hAL ? hBL : hAL);
    {
      dim3 g(PAD8(CDIV(nd, 128)), 8);
      mfma_gemm<<<g, 256, 0, stream>>>(xbH, xbL, IhH + (size_t)hop * 262144,
          hCurH, hCurL, HhH + (size_t)hop * 262144,
          hop ? 2 : 1, nd, 1024, 256,
          nullptr, nullptr, nullptr, nullptr, nullptr,
          c, c, hNewH, hNewL, hop < 2 ? xW : nullptr, hop == 0 ? 1 : 0, 0);
    }
    hCurH = hNewH; hCurL = hNewL;
  }

  // ---- output projection (N=128): d_out = h @ Wout + b_out ----
  {
    dim3 g(PAD8(CDIV(7500, 128)), 1);
    mfma_gemm<<<g, 256, 0, stream>>>(hCurH, hCurL, WoH,
        nullptr, nullptr, nullptr, 1, 7500, 128, 256,
        b_out, (float*)d_out, nullptr, nullptr, nullptr, nullptr, nullptr,
        nullptr, nullptr, nullptr, 0, 0);
  }
}

// Round 17
// 564.852 us; speedup vs baseline: 1.2303x; 1.0049x over previous
//
#include <hip/hip_runtime.h>
#include <cstddef>
#include <cstdint>

#define CDIV(a,b) (((a)+(b)-1)/(b))
#define PAD8(x) ((((x)+7)/8)*8)
#define NEG_SLOPE 0.2f

typedef unsigned short u16;
typedef __attribute__((ext_vector_type(8))) short bf16x8;
typedef __attribute__((ext_vector_type(4))) float f32x4;

// ---------- bf16 helpers (explicit RNE, hi/lo split: v ~= hi + lo, ~17 mantissa bits) ----------
__device__ __forceinline__ u16 bf16_rne(float v){
  unsigned u = __float_as_uint(v);
  unsigned r = (u + 0x7FFFu + ((u >> 16) & 1u)) >> 16;
  return (u16)r;
}
__device__ __forceinline__ float bf16_to_f(u16 h){
  return __uint_as_float(((unsigned)h) << 16);
}
__device__ __forceinline__ void f2hilo(float v, u16& h, u16& l){
  h = bf16_rne(v);
  float r = v - bf16_to_f(h);
  l = bf16_rne(r);
}
// interleaved word: (hi<<16)|lo ; value = asfloat(w&0xFFFF0000) + asfloat(w<<16)
__device__ __forceinline__ float dec_w(unsigned w){
  return __uint_as_float(w & 0xFFFF0000u) + __uint_as_float(w << 16);
}

// ---------- tile-packed operand layout (round-8, verified; GEMM A/B operands only) ----
// Matrix [rows][K] stored as bricks: 128-row block r0, k-tile t (BK=32) -> contiguous
// 4096 u16 (8KB). Element (rr,k) at phys chunk (s+(rr>>1))&3 (s=(k&31)>>3): LDS bank
// swizzle PRE-BAKED, GEMM staging is a pure linear 8KB copy (ideal DRAM bursts).
__device__ __forceinline__ size_t pk_off(int row, int k, int nbk){
  int r0 = row >> 7, rr = row & 127;
  int t = k >> 5, kk = k & 31;
  int s = kk >> 3, w = kk & 7;
  int phys = (s + (rr >> 1)) & 3;
  return ((size_t)(r0 * nbk + t) * 128 + rr) * 32 + phys * 8 + w;
}

__device__ __forceinline__ float sigmf(float x){ return 1.f / (1.f + expf(-x)); }

// ---------- async global->LDS, 16B per lane ----------
__device__ __forceinline__ void gload16(const void* g, void* l){
  __builtin_amdgcn_global_load_lds((const __attribute__((address_space(1))) void*)g,
                                   (__attribute__((address_space(3))) void*)l, 16, 0, 0);
}

// =====================================================================================
// Fused MFMA GEMM — SINGLE untemplated instantiation; 2-PHASE numerics:
//   C = sum_pairs (Ah + Al) @ Bh^T   (activations hi/lo ~17-bit, weights bf16;
//   absmax measured UNCHANGED vs 3-phase, rounds 13+16).
// 128x128 tile, 4 waves, BK=32, double-buffered LDS (2 x 24KB = 48KB -> 3 blocks/CU),
// counted vmcnt(6) depth-2 prefetch, 32 MFMA per 2-barrier window.
// ROUND-17: per-block K-TILE PHASE ROTATION — each block starts its K-loop at
// t0 = (bx + 3*by) & (NT-1) and wraps (accumulation is order-independent).
// Co-resident blocks then sit at different pipeline phases, so one block's MFMA
// window covers the others' stage/vmcnt/barrier stalls and staging bursts
// desynchronize (the ~2000 cyc/tile lockstep stall diagnosed in r16).
// Operands tile-packed (pk_off): stage = linear 8KB copies. Grid (m-blocks %8 padded,
// n-blocks): column-siblings share an XCD -> A fetched ~once per XCD L2.
// NOTE (rounds 7+11): 256^2 tile at 1 block/CU regresses. NOTE (rounds 13-15): keep
// exactly ONE GEMM kernel in the TU (co-instantiation costs ~30-40us elsewhere).
// Epilogues: (a) f32 C (+bias), (b) packed hi/lo and/or LINEAR u32 interleaved
// (+bias, optional tanh), (c) fused LSTM (gate-interleaved B; writes c f32 +
// packed h hi/lo + linear u32 h for the next hop's gather/alpha).
// =====================================================================================
__global__ __launch_bounds__(256, 2) void mfma_gemm(
    const u16* __restrict__ Ah0, const u16* __restrict__ Al0,
    const u16* __restrict__ Bh0,
    const u16* __restrict__ Ah1, const u16* __restrict__ Al1,
    const u16* __restrict__ Bh1,
    int npairs, int M, int N, int K,
    const float* __restrict__ bias, float* __restrict__ Cf,
    u16* __restrict__ outHi, u16* __restrict__ outLo, unsigned* __restrict__ outW,
    const float* __restrict__ cIn, float* __restrict__ cOut,
    u16* __restrict__ hH, u16* __restrict__ hL, unsigned* __restrict__ hW,
    int lstm_first, int tanh_out)
{
  if ((int)(blockIdx.x * 128) >= M) return;   // pad-%8 guard (block-uniform)
  __shared__ u16 smem[2 * 12288];  // per buf: Ah@0 Al@4096 Bh@8192 (u16 units)
  const int tid = threadIdx.x;
  const int lane = tid & 63, wv = tid >> 6;
  const int l15 = lane & 15, lq = lane >> 4;
  const int wr = wv >> 1, wc = wv & 1;
  const int bm = blockIdx.x * 128, bn = blockIdx.y * 128;
  const int nbk = K >> 5, NT = npairs * nbk;          // NT is a power of two (4/8/16)
  const size_t Abase = (size_t)(bm >> 7) * nbk * 4096;
  const size_t Bbase = (size_t)(bn >> 7) * nbk * 4096;

  f32x4 acc[4][4];
  #pragma unroll
  for (int m = 0; m < 4; m++)
    #pragma unroll
    for (int n = 0; n < 4; n++) acc[m][n] = (f32x4){0.f, 0.f, 0.f, 0.f};

  // staging: thread's chunk c = i*256+tid -> linear 16B at brick offset c*16
  size_t goff[2]; int ldso2[2];
  #pragma unroll
  for (int i = 0; i < 2; i++){
    goff[i]  = (size_t)(i * 256 + tid) * 8;        // u16 units, contiguous
    ldso2[i] = (i * 256 + (tid & 192)) * 8;        // wave-uniform LDS base
  }

  // fragment read offsets (u16 units within a buffer); phys chunk = (lq + (r>>1)) & 3
  int aoff[4], boff[4];
  #pragma unroll
  for (int m = 0; m < 4; m++){
    int r = wr * 64 + m * 16 + l15;
    aoff[m] = r * 32 + ((lq + (r >> 1)) & 3) * 8;
  }
  #pragma unroll
  for (int n = 0; n < 4; n++){
    int r = wc * 64 + n * 16 + l15;
    boff[n] = r * 32 + ((lq + (r >> 1)) & 3) * 8;
  }

  auto stage = [&](int buf, int t){
    int q = (npairs > 1 && t >= nbk) ? 1 : 0;
    const u16* A_h = q ? Ah1 : Ah0;  const u16* A_l = q ? Al1 : Al0;
    const u16* B_h = q ? Bh1 : Bh0;
    int tl = q ? t - nbk : t;
    size_t ab = Abase + (size_t)tl * 4096;
    size_t bb = Bbase + (size_t)tl * 4096;
    u16* sb = smem + buf * 12288;
    #pragma unroll
    for (int i = 0; i < 2; i++){
      gload16(A_h + ab + goff[i], sb + ldso2[i]);
      gload16(A_l + ab + goff[i], sb + 4096 + ldso2[i]);
      gload16(B_h + bb + goff[i], sb + 8192 + ldso2[i]);
    }
  };

  // per-block K-tile phase rotation (accumulation order-independent)
  const int t0 = (blockIdx.x + 3 * blockIdx.y) & (NT - 1);
  stage(0, t0);                 // 6 loads/wave outstanding
  int cur = 0;
  #pragma unroll 1
  for (int i = 0; i < NT; i++){
    if (i + 1 < NT){
      int tn = t0 + i + 1; if (tn >= NT) tn -= NT;
      stage(cur ^ 1, tn);       // +6 -> up to 12 outstanding
      asm volatile("s_waitcnt vmcnt(6)" ::: "memory");   // tile-i landed; next in flight
    } else {
      asm volatile("s_waitcnt vmcnt(0)" ::: "memory");
    }
    __builtin_amdgcn_sched_barrier(0);
    __builtin_amdgcn_s_barrier();        // tile visible to all waves
    __builtin_amdgcn_sched_barrier(0);
    const u16* sb = smem + cur * 12288;
    bf16x8 ah[4], al[4], bh[4];
    #pragma unroll
    for (int m = 0; m < 4; m++){
      ah[m] = *(const bf16x8*)(sb + aoff[m]);
      al[m] = *(const bf16x8*)(sb + 4096 + aoff[m]);
    }
    #pragma unroll
    for (int n = 0; n < 4; n++){
      bh[n] = *(const bf16x8*)(sb + 8192 + boff[n]);
    }
    #pragma unroll
    for (int m = 0; m < 4; m++)
      #pragma unroll
      for (int n = 0; n < 4; n++){
        acc[m][n] = __builtin_amdgcn_mfma_f32_16x16x32_bf16(ah[m], bh[n], acc[m][n], 0, 0, 0);
        acc[m][n] = __builtin_amdgcn_mfma_f32_16x16x32_bf16(al[m], bh[n], acc[m][n], 0, 0, 0);
      }
    __builtin_amdgcn_sched_barrier(0);
    __builtin_amdgcn_s_barrier();        // buf[cur] released; NO vmcnt drain
    cur ^= 1;
  }

  // epilogue: C/D layout col=lane&15, row=(lane>>4)*4+j (m89/m91-verified)
  const int rb = bm + wr * 64 + lq * 4;
  if (cOut){
    // LSTM mode: lane owns channel ch; n-frag index == gate (i,f,g,o)
    const int ch = (bn >> 2) + wc * 16 + l15;
    #pragma unroll
    for (int m = 0; m < 4; m++){
      #pragma unroll
      for (int j = 0; j < 4; j++){
        int row = rb + m * 16 + j;
        if (row >= M) continue;
        float i_ = acc[m][0][j], f_ = acc[m][1][j], g_ = acc[m][2][j], o_ = acc[m][3][j];
        float si = sigmf(i_), tg = tanhf(g_), so = sigmf(o_);
        size_t loff = (size_t)row * 256 + ch;
        float cn = lstm_first ? si * tg : sigmf(f_) * cIn[loff] + si * tg;
        float hn = so * tanhf(cn);
        cOut[loff] = cn;
        u16 hh, hl; f2hilo(hn, hh, hl);
        size_t pko = pk_off(row, ch, 8);
        hH[pko] = hh; hL[pko] = hl;
        if (hW) hW[loff] = ((unsigned)hh << 16) | (unsigned)hl;   // linear copy
      }
    }
  } else {
    const int cb = bn + wc * 64 + l15;
    #pragma unroll
    for (int n = 0; n < 4; n++){
      int col = cb + n * 16;
      float bv = bias ? bias[col] : 0.f;
      #pragma unroll
      for (int m = 0; m < 4; m++){
        #pragma unroll
        for (int j = 0; j < 4; j++){
          int row = rb + m * 16 + j;
          if (row >= M) continue;
          float v = acc[m][n][j] + bv;
          if (tanh_out) v = tanhf(v);
          if (Cf) Cf[(size_t)row * N + col] = v;
          if (outHi || outW){
            u16 hh, hl; f2hilo(v, hh, hl);
            if (outHi){
              size_t pko = pk_off(row, col, 8);
              outHi[pko] = hh; outLo[pko] = hl;
            }
            if (outW) outW[(size_t)row * 256 + col] = ((unsigned)hh << 16) | (unsigned)hl;
          }
        }
      }
    }
  }
}

// ---------- feats f32 [60000][128] -> packed hi/lo bf16 (nbk=4), 4 elems/thread ----------
__global__ __launch_bounds__(256) void cvt_feats(const float* __restrict__ in,
    u16* __restrict__ hi, u16* __restrict__ lo, int nrow){
  int i = blockIdx.x * 256 + threadIdx.x;       // quad index
  int row = i >> 5, k4 = (i & 31) * 4;
  if (row >= nrow) return;
  float4 v = *(const float4*)(in + (size_t)row * 128 + k4);
  ushort4 h4, l4;
  f2hilo(v.x, h4.x, l4.x); f2hilo(v.y, h4.y, l4.y);
  f2hilo(v.z, h4.z, l4.z); f2hilo(v.w, h4.w, l4.w);
  size_t off = pk_off(row, k4, 4);              // w in {0,4}: ushort4 stays in-chunk
  *(ushort4*)(hi + off) = h4;
  *(ushort4*)(lo + off) = l4;
}

// ---------- one-shot weight prep: transpose/permute + PACKED bf16 (hi only) ----------
// Reads coalesced over n. W_ih/W_hh rows PERMUTED to gate-interleaved layout:
// orig row (gate*256+ch) -> n' = (ch>>4)*64 + gate*16 + (ch&15) (epilogue LSTM fusion).
__global__ __launch_bounds__(256) void prep_w(const float* __restrict__ Win,
    const float* __restrict__ Wsrc, const float* __restrict__ Wih,
    const float* __restrict__ Whh, const float* __restrict__ Wout,
    u16* WinH, u16* WsH, u16* IhH, u16* HhH, u16* WoH){
  int idx = blockIdx.x * 256 + threadIdx.x;
  float v; u16 *ph; size_t off;
  if (idx < 32768){                       // WinT [256][128] <- Win[128][256]; nbk=4
    int n = idx & 255, k = idx >> 8;
    v = Win[k * 256 + n]; ph = WinH; off = pk_off(n, k, 4);
  } else if (idx < 229376){               // WsT [3][256][256] <- Wsrc^T; nbk=8
    int t = idx - 32768; int hop = t >> 16, r = t & 65535, n = r & 255, k = r >> 8;
    v = Wsrc[hop * 65536 + k * 256 + n]; ph = WsH;
    off = (size_t)hop * 65536 + pk_off(n, k, 8);
  } else if (idx < 1015808){              // W_ih [3][1024][256], gate-interleaved; nbk=8
    int t = idx - 229376;
    int hop = t >> 18, r = (t >> 8) & 1023, k = t & 255;
    int gate = r >> 8, ch = r & 255;
    int np = ((ch >> 4) << 6) + (gate << 4) + (ch & 15);
    v = Wih[t]; ph = IhH;
    off = (size_t)hop * 262144 + pk_off(np, k, 8);
  } else if (idx < 1802240){              // W_hh, same permutation
    int t = idx - 1015808;
    int hop = t >> 18, r = (t >> 8) & 1023, k = t & 255;
    int gate = r >> 8, ch = r & 255;
    int np = ((ch >> 4) << 6) + (gate << 4) + (ch & 15);
    v = Whh[t]; ph = HhH;
    off = (size_t)hop * 262144 + pk_off(np, k, 8);
  } else if (idx < 1835008){              // WoT [128][256] <- Wout^T; nbk=8
    int t = idx - 1802240; int n = t & 127, k = t >> 7;
    v = Wout[k * 128 + n]; ph = WoH; off = pk_off(n, k, 8);
  } else return;
  ph[off] = bf16_rne(v);
}

// ---------- w_s[hop] = Wsrc[hop]@a_s, w_d[hop] = Wdst[hop]@a_d (row dots, f32) ----------
__global__ __launch_bounds__(256) void prep_wvec(const float* __restrict__ Wsrc,
    const float* __restrict__ Wdst, const float* __restrict__ as_,
    const float* __restrict__ ad_, float* __restrict__ wsv, float* __restrict__ wdv){
  int wid = blockIdx.x * 4 + (threadIdx.x >> 6), lane = threadIdx.x & 63;
  if (wid >= 6 * 256) return;
  int vec = wid >> 8, i = wid & 255;
  int hop = vec >> 1; bool isd = vec & 1;
  const float* Wrow = (isd ? Wdst : Wsrc) + (size_t)hop * 65536 + (size_t)i * 256;
  const float* a = (isd ? ad_ : as_) + hop * 256;
  float4 w4 = *(const float4*)(Wrow + lane * 4);
  float4 a4 = *(const float4*)(a + lane * 4);
  float v = w4.x * a4.x + w4.y * a4.y + w4.z * a4.z + w4.w * a4.w;
  #pragma unroll
  for (int off = 32; off; off >>= 1) v += __shfl_down(v, off);
  if (!lane) (isd ? wdv : wsv)[hop * 256 + i] = v;
}

// ---------- alpha from LINEAR interleaved x: coalesced uint4 row reads ----------
// Rows < nd need BOTH the src-dot (vs wsv) and dst-dot (vs wdv): one row pass.
__global__ __launch_bounds__(256) void alpha_mv(const unsigned* __restrict__ xW,
    const float* __restrict__ wsv, const float* __restrict__ wdv,
    float* __restrict__ as_out, float* __restrict__ ad_out, int ns, int nd){
  int row = blockIdx.x * 4 + (threadIdx.x >> 6), lane = threadIdx.x & 63;
  if (row >= ns) return;
  uint4 w = *(const uint4*)(xW + (size_t)row * 256 + lane * 4);
  float x0 = dec_w(w.x), x1 = dec_w(w.y), x2 = dec_w(w.z), x3 = dec_w(w.w);
  float4 s4 = *(const float4*)(wsv + lane * 4);
  float vs = x0 * s4.x + x1 * s4.y + x2 * s4.z + x3 * s4.w;
  bool both = row < nd;
  float vd = 0.f;
  if (both){
    float4 d4 = *(const float4*)(wdv + lane * 4);
    vd = x0 * d4.x + x1 * d4.y + x2 * d4.z + x3 * d4.w;
  }
  #pragma unroll
  for (int off2 = 32; off2; off2 >>= 1){
    vs += __shfl_down(vs, off2);
    vd += __shfl_down(vd, off2);
  }
  if (!lane){
    as_out[row] = vs;
    if (both) ad_out[row] = vd;
  }
}

// ---------- edges + self-loops: leaky-relu alpha -> e=exp(alpha) directly, degree ----
// NO-MAX softmax (round-12, exact up to fp noise: alphas O(1), softmax shift-invariant)
__global__ __launch_bounds__(256) void edge_a(const int* __restrict__ src,
    const int* __restrict__ dst, const float* __restrict__ as_, const float* __restrict__ ad_,
    float* __restrict__ e_edge, float* __restrict__ e_self,
    int* __restrict__ cnt, int E, int nd){
  int i = blockIdx.x * 256 + threadIdx.x;
  if (i < E){
    int s = src[i], d = dst[i];
    float al = as_[s] + ad_[d];
    al = al > 0.f ? al : NEG_SLOPE * al;
    e_edge[i] = expf(al);
    atomicAdd(&cnt[d], 1);
  } else if (i < E + nd){
    int j = i - E;
    float al = as_[j] + ad_[j];
    al = al > 0.f ? al : NEG_SLOPE * al;
    e_self[j] = expf(al);
  }
}

// ---------- scan, 2 dispatches ----------
__global__ __launch_bounds__(256) void scan_part(const int* __restrict__ cnt,
    int* __restrict__ part, int n){
  __shared__ int ws_[4];
  int lane = threadIdx.x & 63, wv = threadIdx.x >> 6;
  int i = blockIdx.x * 256 + threadIdx.x;
  int v = (i < n) ? cnt[i] : 0;
  #pragma unroll
  for (int off = 32; off; off >>= 1) v += __shfl_down(v, off);
  if (!lane) ws_[wv] = v;
  __syncthreads();
  if (!threadIdx.x) part[blockIdx.x] = ws_[0] + ws_[1] + ws_[2] + ws_[3];
}
__global__ __launch_bounds__(256) void scan_fin(const int* __restrict__ cnt,
    const int* __restrict__ part, int* __restrict__ base, int* __restrict__ cursor,
    int n, int nb){
  __shared__ int ps[128];
  __shared__ int wtot[4];
  int t = threadIdx.x;
  if (t < 128) ps[t] = (t < nb) ? part[t] : 0;
  __syncthreads();
  #pragma unroll
  for (int off = 1; off < 128; off <<= 1){
    int v = (t < 128 && t >= off) ? ps[t - off] : 0;
    __syncthreads();
    if (t < 128) ps[t] += v;
    __syncthreads();
  }
  int lane = t & 63, wv = t >> 6;
  int i = blockIdx.x * 256 + t;
  int v = (i < n) ? cnt[i] : 0;
  int incl = v;
  #pragma unroll
  for (int off = 1; off < 64; off <<= 1){
    int s = __shfl_up(incl, off);
    if (lane >= off) incl += s;
  }
  if (lane == 63) wtot[wv] = incl;
  __syncthreads();
  int woff = blockIdx.x ? ps[blockIdx.x - 1] : 0;
  for (int w = 0; w < wv; w++) woff += wtot[w];
  int excl = woff + incl - v;
  if (i < n){ base[i] = excl; cursor[i] = excl; }
}

// ---------- CSR fill (e already computed in edge_a) ----------
__global__ __launch_bounds__(256) void edge_b(const int* __restrict__ src,
    const int* __restrict__ dst, const float* __restrict__ e_edge,
    int* __restrict__ cursor, int* __restrict__ csr_src, float* __restrict__ csr_e, int E){
  int e = blockIdx.x * 256 + threadIdx.x;
  if (e >= E) return;
  int d = dst[e];
  int pos = atomicAdd(&cursor[d], 1);
  csr_src[pos] = src[e];
  csr_e[pos] = e_edge[e];
}

// ---------- gather: agg[j] = (sum_e w_e x[src] + w_self x[j]) / sum w ----------
// x from LINEAR interleaved u32 rows (1KB contiguous per edge, coalesced uint4/lane)
// with 8-deep independent-load unroll (MLP). Output packed (GEMM A-operand).
__global__ __launch_bounds__(256) void gather_agg(const unsigned* __restrict__ xW,
    const int* __restrict__ base, const int* __restrict__ cnt,
    const int* __restrict__ csr_src, const float* __restrict__ csr_e,
    const float* __restrict__ e_self,
    u16* __restrict__ aggH, u16* __restrict__ aggL, int n){
  int wv = threadIdx.x >> 6, lane = threadIdx.x & 63;
  int j = blockIdx.x * 4 + wv;
  if (j >= n) return;
  int b0 = base[j], cn = cnt[j];
  float a0 = 0.f, a1 = 0.f, a2 = 0.f, a3 = 0.f, ds = 0.f;
  int k = 0;
  for (; k + 8 <= cn; k += 8){
    int ss[8]; float ee[8]; uint4 ww[8];
    #pragma unroll
    for (int u = 0; u < 8; u++){ ss[u] = csr_src[b0 + k + u]; ee[u] = csr_e[b0 + k + u]; }
    #pragma unroll
    for (int u = 0; u < 8; u++) ww[u] = *(const uint4*)(xW + (size_t)ss[u] * 256 + lane * 4);
    #pragma unroll
    for (int u = 0; u < 8; u++){
      float e = ee[u];
      a0 += e * dec_w(ww[u].x); a1 += e * dec_w(ww[u].y);
      a2 += e * dec_w(ww[u].z); a3 += e * dec_w(ww[u].w);
      ds += e;
    }
  }
  for (; k < cn; k++){
    int s = csr_src[b0 + k];
    float e = csr_e[b0 + k];
    uint4 w = *(const uint4*)(xW + (size_t)s * 256 + lane * 4);
    a0 += e * dec_w(w.x); a1 += e * dec_w(w.y);
    a2 += e * dec_w(w.z); a3 += e * dec_w(w.w);
    ds += e;
  }
  float es = e_self[j];
  {
    uint4 w = *(const uint4*)(xW + (size_t)j * 256 + lane * 4);
    a0 += es * dec_w(w.x); a1 += es * dec_w(w.y);
    a2 += es * dec_w(w.z); a3 += es * dec_w(w.w);
    ds += es;
  }
  float inv = 1.f / ds;
  ushort4 H4, L4;
  f2hilo(a0 * inv, H4.x, L4.x); f2hilo(a1 * inv, H4.y, L4.y);
  f2hilo(a2 * inv, H4.z, L4.z); f2hilo(a3 * inv, H4.w, L4.w);
  size_t off = pk_off(j, lane * 4, 8);
  *(ushort4*)(aggH + off) = H4;
  *(ushort4*)(aggL + off) = L4;
}

extern "C" void kernel_launch(void* const* d_in, const int* in_sizes, int n_in,
                              void* d_out, int out_size, void* d_ws, size_t ws_size,
                              hipStream_t stream){
  const float* feats   = (const float*)d_in[0];
  const float* Win     = (const float*)d_in[1];
  const float* b_in    = (const float*)d_in[2];
  const float* Wsrc    = (const float*)d_in[3];
  const float* Wdst    = (const float*)d_in[4];
  const float* att_src = (const float*)d_in[5];
  const float* att_dst = (const float*)d_in[6];
  const float* gat_b   = (const float*)d_in[7];
  const float* W_ih    = (const float*)d_in[8];
  const float* W_hh    = (const float*)d_in[9];
  const float* Wout    = (const float*)d_in[10];
  const float* b_out   = (const float*)d_in[11];
  const int* srcs[3] = {(const int*)d_in[12], (const int*)d_in[14], (const int*)d_in[16]};
  const int* dsts[3] = {(const int*)d_in[13], (const int*)d_in[15], (const int*)d_in[17]};
  (void)in_sizes; (void)n_in; (void)out_size; (void)ws_size;

  const int ns_a[3] = {60000, 30000, 15000};
  const int nd_a[3] = {30000, 15000, 7500};
  const int E_a[3]  = {480000, 240000, 120000};

  // ---- workspace layout (~231 MiB), aliasing lifetime-checked ----
  char* w = (char*)d_ws;
  unsigned* xW = (unsigned*)(w + 0);              // linear interleaved x rows, 60032x256 u32
  u16* featsH  = (u16*)(w + 61500000);            // packed 60032x128; dead after inproj
  u16* featsL  = (u16*)(w + 77000000);
  float* c     = (float*)(w + 61500000);          // [30000][256] f32; alias feats
                                                  // (feats dead after inproj; c first written hop0 gates)
  u16* aggH    = (u16*)(w + 92500000);            // packed 30080x256
  u16* aggL    = (u16*)(w + 108000000);
  u16* hAH     = (u16*)(w + 123500000);           // packed h ping-pong A
  u16* hAL     = (u16*)(w + 139000000);
  u16* hBH     = (u16*)(w + 154500000);           // set B
  u16* hBL     = (u16*)(w + 170000000);
  u16* xbH     = (u16*)(w + 185500000);
  u16* xbL     = (u16*)(w + 201000000);
  u16* WinH = (u16*)(w + 216500000);              // weight hi-only (2-phase GEMM)
  u16* WsH  = WinH + 32768;
  u16* IhH  = WsH + 196608;
  u16* HhH  = IhH + 786432;
  u16* WoH  = HhH + 786432;
  float* wsv = (float*)(w + 224200000); float* wdv = wsv + 768;
  float* alpha_s = wdv + 768;
  float* alpha_d = alpha_s + 60000;
  float* e_edge  = alpha_d + 30000;               // per-edge exp(alpha)
  float* e_self  = e_edge + 480000;               // per-node self exp(alpha)
  int* cnt       = (int*)(e_self + 30000);
  int* base      = cnt + 30000;
  int* cursor    = base + 30000;
  int* part      = cursor + 30000;                // scan partials (<=128)
  int* csr_src   = part + 256;
  float* csr_e   = (float*)(csr_src + 480000);

  // ---- one-time prep (inputs only) ----
  prep_w<<<7168, 256, 0, stream>>>(Win, Wsrc, W_ih, W_hh, Wout,
      WinH, WsH, IhH, HhH, WoH);
  prep_wvec<<<384, 256, 0, stream>>>(Wsrc, Wdst, att_src, att_dst, wsv, wdv);
  cvt_feats<<<7500, 256, 0, stream>>>(feats, featsH, featsL, 60000);

  // ---- input projection: x0 (linear interleaved) = feats @ Win + b_in ----
  {
    dim3 g(PAD8(CDIV(60000, 128)), 2);
    mfma_gemm<<<g, 256, 0, stream>>>(featsH, featsL, WinH,
        nullptr, nullptr, nullptr, 1, 60000, 256, 128,
        b_in, nullptr, nullptr, nullptr, xW, nullptr, nullptr,
        nullptr, nullptr, nullptr, 0, 0);
  }

  u16* hCurH = hAH; u16* hCurL = hAL;   // packed h from previous hop (pair-1 A-op)
  for (int hop = 0; hop < 3; hop++){
    const int ns = ns_a[hop], nd = nd_a[hop], E = E_a[hop];
    const int nb = CDIV(nd, 256);
    hipMemsetAsync(cnt, 0, (size_t)nd * 4, stream);

    alpha_mv<<<CDIV(ns, 4), 256, 0, stream>>>(xW, wsv + hop * 256, wdv + hop * 256,
        alpha_s, alpha_d, ns, nd);
    edge_a<<<CDIV(E + nd, 256), 256, 0, stream>>>(srcs[hop], dsts[hop], alpha_s, alpha_d,
        e_edge, e_self, cnt, E, nd);
    scan_part<<<nb, 256, 0, stream>>>(cnt, part, nd);
    scan_fin<<<nb, 256, 0, stream>>>(cnt, part, base, cursor, nd, nb);
    edge_b<<<CDIV(E, 256), 256, 0, stream>>>(srcs[hop], dsts[hop], e_edge,
        cursor, csr_src, csr_e, E);
    gather_agg<<<CDIV(nd, 4), 256, 0, stream>>>(xW, base, cnt, csr_src, csr_e,
        e_self, aggH, aggL, nd);

    // xb(packed) = tanh(agg @ WsrcT + gat_b)   [M = nd rows]
    {
      dim3 g(PAD8(CDIV(nd, 128)), 2);
      mfma_gemm<<<g, 256, 0, stream>>>(aggH, aggL, WsH + (size_t)hop * 65536,
          nullptr, nullptr, nullptr, 1, nd, 256, 256,
          gat_b + hop * 256, nullptr, xbH, xbL, nullptr, nullptr, nullptr,
          nullptr, nullptr, nullptr, 0, 1);
    }

    // gates GEMM + fused LSTM; h: packed ping-pong (A-op) + linear xW (next hop's
    // gather/alpha; dead after hop 1 -> skip at hop 2)
    u16* hNewH = (hop == 0) ? hAH : (hCurH == hAH ? hBH : hAH);
    u16* hNewL = (hop == 0) ? hAL : (hCurL == hAL ? hBL : hAL);
    {
      dim3 g(PAD8(CDIV(nd, 128)), 8);
      mfma_gemm<<<g, 256, 0, stream>>>(xbH, xbL, IhH + (size_t)hop * 262144,
          hCurH, hCurL, HhH + (size_t)hop * 262144,
          hop ? 2 : 1, nd, 1024, 256,
          nullptr, nullptr, nullptr, nullptr, nullptr,
          c, c, hNewH, hNewL, hop < 2 ? xW : nullptr, hop == 0 ? 1 : 0, 0);
    }
    hCurH = hNewH; hCurL = hNewL;
  }

  // ---- output projection (N=128): d_out = h @ Wout + b_out ----
  {
    dim3 g(PAD8(CDIV(7500, 128)), 1);
    mfma_gemm<<<g, 256, 0, stream>>>(hCurH, hCurL, WoH,
        nullptr, nullptr, nullptr, 1, 7500, 128, 256,
        b_out, (float*)d_out, nullptr, nullptr, nullptr, nullptr, nullptr,
        nullptr, nullptr, nullptr, 0, 0);
  }
}

// Round 18
// 499.226 us; speedup vs baseline: 1.3921x; 1.1315x over previous
//
#include <hip/hip_runtime.h>
#include <cstddef>
#include <cstdint>

#define CDIV(a,b) (((a)+(b)-1)/(b))
#define PAD8(x) ((((x)+7)/8)*8)
#define NEG_SLOPE 0.2f

typedef unsigned short u16;
typedef __attribute__((ext_vector_type(8))) short bf16x8;
typedef __attribute__((ext_vector_type(4))) float f32x4;

// ---------- bf16 helpers (explicit RNE, hi/lo split: v ~= hi + lo, ~17 mantissa bits) ----------
__device__ __forceinline__ u16 bf16_rne(float v){
  unsigned u = __float_as_uint(v);
  unsigned r = (u + 0x7FFFu + ((u >> 16) & 1u)) >> 16;
  return (u16)r;
}
__device__ __forceinline__ float bf16_to_f(u16 h){
  return __uint_as_float(((unsigned)h) << 16);
}
__device__ __forceinline__ void f2hilo(float v, u16& h, u16& l){
  h = bf16_rne(v);
  float r = v - bf16_to_f(h);
  l = bf16_rne(r);
}

// ---------- tile-packed operand layout (round-8, verified; GEMM A/B operands only) ----
// Matrix [rows][K] stored as bricks: 128-row block r0, k-tile t (BK=32) -> contiguous
// 4096 u16 (8KB). Element (rr,k) at phys chunk (s+(rr>>1))&3 (s=(k&31)>>3): LDS bank
// swizzle PRE-BAKED, GEMM staging is a pure linear 8KB copy (ideal DRAM bursts).
__device__ __forceinline__ size_t pk_off(int row, int k, int nbk){
  int r0 = row >> 7, rr = row & 127;
  int t = k >> 5, kk = k & 31;
  int s = kk >> 3, w = kk & 7;
  int phys = (s + (rr >> 1)) & 3;
  return ((size_t)(r0 * nbk + t) * 128 + rr) * 32 + phys * 8 + w;
}

__device__ __forceinline__ float sigmf(float x){ return 1.f / (1.f + expf(-x)); }

// ---------- async global->LDS, 16B per lane ----------
__device__ __forceinline__ void gload16(const void* g, void* l){
  __builtin_amdgcn_global_load_lds((const __attribute__((address_space(1))) void*)g,
                                   (__attribute__((address_space(3))) void*)l, 16, 0, 0);
}

// =====================================================================================
// Fused MFMA GEMM — SINGLE untemplated instantiation; 2-PHASE numerics:
//   C = sum_pairs (Ah + Al) @ Bh^T   (activations hi/lo ~17-bit, weights bf16;
//   absmax measured UNCHANGED vs 3-phase, rounds 13+16).
// 128x128 tile, 4 waves, BK=32, double-buffered LDS (2 x 24KB = 48KB -> 3 blocks/CU),
// counted vmcnt(6) depth-2 prefetch, 32 MFMA per 2-barrier window.
// Per-block K-tile phase rotation (r17; time-neutral, kept).
// ROUND-18: the LINEAR x side-copy for gather/alpha is now bf16-HI ONLY (u16 rows,
// 512B/row) — halves the dominant non-GEMM read traffic + epilogue copy writes.
// Precision: one extra bf16 rounding at gather input, attenuated by the small-weight
// projection chain (r13/r16 logic); packed GEMM A-operands keep full hi/lo.
// NOTE (rounds 7+11): 256^2 tile at 1 block/CU regresses. NOTE (rounds 13-15): keep
// exactly ONE GEMM kernel in the TU (co-instantiation costs ~30-40us elsewhere).
// Epilogues: (a) f32 C (+bias), (b) packed hi/lo and/or LINEAR u16-hi (+bias,
// optional tanh), (c) fused LSTM (gate-interleaved B; writes c f32 + packed h hi/lo
// + linear u16 h for the next hop's gather/alpha).
// =====================================================================================
__global__ __launch_bounds__(256, 2) void mfma_gemm(
    const u16* __restrict__ Ah0, const u16* __restrict__ Al0,
    const u16* __restrict__ Bh0,
    const u16* __restrict__ Ah1, const u16* __restrict__ Al1,
    const u16* __restrict__ Bh1,
    int npairs, int M, int N, int K,
    const float* __restrict__ bias, float* __restrict__ Cf,
    u16* __restrict__ outHi, u16* __restrict__ outLo, u16* __restrict__ outLin,
    const float* __restrict__ cIn, float* __restrict__ cOut,
    u16* __restrict__ hH, u16* __restrict__ hL, u16* __restrict__ hLin,
    int lstm_first, int tanh_out)
{
  if ((int)(blockIdx.x * 128) >= M) return;   // pad-%8 guard (block-uniform)
  __shared__ u16 smem[2 * 12288];  // per buf: Ah@0 Al@4096 Bh@8192 (u16 units)
  const int tid = threadIdx.x;
  const int lane = tid & 63, wv = tid >> 6;
  const int l15 = lane & 15, lq = lane >> 4;
  const int wr = wv >> 1, wc = wv & 1;
  const int bm = blockIdx.x * 128, bn = blockIdx.y * 128;
  const int nbk = K >> 5, NT = npairs * nbk;          // NT is a power of two (4/8/16)
  const size_t Abase = (size_t)(bm >> 7) * nbk * 4096;
  const size_t Bbase = (size_t)(bn >> 7) * nbk * 4096;

  f32x4 acc[4][4];
  #pragma unroll
  for (int m = 0; m < 4; m++)
    #pragma unroll
    for (int n = 0; n < 4; n++) acc[m][n] = (f32x4){0.f, 0.f, 0.f, 0.f};

  // staging: thread's chunk c = i*256+tid -> linear 16B at brick offset c*16
  size_t goff[2]; int ldso2[2];
  #pragma unroll
  for (int i = 0; i < 2; i++){
    goff[i]  = (size_t)(i * 256 + tid) * 8;        // u16 units, contiguous
    ldso2[i] = (i * 256 + (tid & 192)) * 8;        // wave-uniform LDS base
  }

  // fragment read offsets (u16 units within a buffer); phys chunk = (lq + (r>>1)) & 3
  int aoff[4], boff[4];
  #pragma unroll
  for (int m = 0; m < 4; m++){
    int r = wr * 64 + m * 16 + l15;
    aoff[m] = r * 32 + ((lq + (r >> 1)) & 3) * 8;
  }
  #pragma unroll
  for (int n = 0; n < 4; n++){
    int r = wc * 64 + n * 16 + l15;
    boff[n] = r * 32 + ((lq + (r >> 1)) & 3) * 8;
  }

  auto stage = [&](int buf, int t){
    int q = (npairs > 1 && t >= nbk) ? 1 : 0;
    const u16* A_h = q ? Ah1 : Ah0;  const u16* A_l = q ? Al1 : Al0;
    const u16* B_h = q ? Bh1 : Bh0;
    int tl = q ? t - nbk : t;
    size_t ab = Abase + (size_t)tl * 4096;
    size_t bb = Bbase + (size_t)tl * 4096;
    u16* sb = smem + buf * 12288;
    #pragma unroll
    for (int i = 0; i < 2; i++){
      gload16(A_h + ab + goff[i], sb + ldso2[i]);
      gload16(A_l + ab + goff[i], sb + 4096 + ldso2[i]);
      gload16(B_h + bb + goff[i], sb + 8192 + ldso2[i]);
    }
  };

  // per-block K-tile phase rotation (accumulation order-independent)
  const int t0 = (blockIdx.x + 3 * blockIdx.y) & (NT - 1);
  stage(0, t0);                 // 6 loads/wave outstanding
  int cur = 0;
  #pragma unroll 1
  for (int i = 0; i < NT; i++){
    if (i + 1 < NT){
      int tn = t0 + i + 1; if (tn >= NT) tn -= NT;
      stage(cur ^ 1, tn);       // +6 -> up to 12 outstanding
      asm volatile("s_waitcnt vmcnt(6)" ::: "memory");   // tile-i landed; next in flight
    } else {
      asm volatile("s_waitcnt vmcnt(0)" ::: "memory");
    }
    __builtin_amdgcn_sched_barrier(0);
    __builtin_amdgcn_s_barrier();        // tile visible to all waves
    __builtin_amdgcn_sched_barrier(0);
    const u16* sb = smem + cur * 12288;
    bf16x8 ah[4], al[4], bh[4];
    #pragma unroll
    for (int m = 0; m < 4; m++){
      ah[m] = *(const bf16x8*)(sb + aoff[m]);
      al[m] = *(const bf16x8*)(sb + 4096 + aoff[m]);
    }
    #pragma unroll
    for (int n = 0; n < 4; n++){
      bh[n] = *(const bf16x8*)(sb + 8192 + boff[n]);
    }
    #pragma unroll
    for (int m = 0; m < 4; m++)
      #pragma unroll
      for (int n = 0; n < 4; n++){
        acc[m][n] = __builtin_amdgcn_mfma_f32_16x16x32_bf16(ah[m], bh[n], acc[m][n], 0, 0, 0);
        acc[m][n] = __builtin_amdgcn_mfma_f32_16x16x32_bf16(al[m], bh[n], acc[m][n], 0, 0, 0);
      }
    __builtin_amdgcn_sched_barrier(0);
    __builtin_amdgcn_s_barrier();        // buf[cur] released; NO vmcnt drain
    cur ^= 1;
  }

  // epilogue: C/D layout col=lane&15, row=(lane>>4)*4+j (m89/m91-verified)
  const int rb = bm + wr * 64 + lq * 4;
  if (cOut){
    // LSTM mode: lane owns channel ch; n-frag index == gate (i,f,g,o)
    const int ch = (bn >> 2) + wc * 16 + l15;
    #pragma unroll
    for (int m = 0; m < 4; m++){
      #pragma unroll
      for (int j = 0; j < 4; j++){
        int row = rb + m * 16 + j;
        if (row >= M) continue;
        float i_ = acc[m][0][j], f_ = acc[m][1][j], g_ = acc[m][2][j], o_ = acc[m][3][j];
        float si = sigmf(i_), tg = tanhf(g_), so = sigmf(o_);
        size_t loff = (size_t)row * 256 + ch;
        float cn = lstm_first ? si * tg : sigmf(f_) * cIn[loff] + si * tg;
        float hn = so * tanhf(cn);
        cOut[loff] = cn;
        u16 hh, hl; f2hilo(hn, hh, hl);
        size_t pko = pk_off(row, ch, 8);
        hH[pko] = hh; hL[pko] = hl;
        if (hLin) hLin[loff] = hh;       // linear bf16-hi copy for gather/alpha
      }
    }
  } else {
    const int cb = bn + wc * 64 + l15;
    #pragma unroll
    for (int n = 0; n < 4; n++){
      int col = cb + n * 16;
      float bv = bias ? bias[col] : 0.f;
      #pragma unroll
      for (int m = 0; m < 4; m++){
        #pragma unroll
        for (int j = 0; j < 4; j++){
          int row = rb + m * 16 + j;
          if (row >= M) continue;
          float v = acc[m][n][j] + bv;
          if (tanh_out) v = tanhf(v);
          if (Cf) Cf[(size_t)row * N + col] = v;
          if (outHi || outLin){
            u16 hh, hl; f2hilo(v, hh, hl);
            if (outHi){
              size_t pko = pk_off(row, col, 8);
              outHi[pko] = hh; outLo[pko] = hl;
            }
            if (outLin) outLin[(size_t)row * 256 + col] = hh;
          }
        }
      }
    }
  }
}

// ---------- feats f32 [60000][128] -> packed hi/lo bf16 (nbk=4), 4 elems/thread ----------
__global__ __launch_bounds__(256) void cvt_feats(const float* __restrict__ in,
    u16* __restrict__ hi, u16* __restrict__ lo, int nrow){
  int i = blockIdx.x * 256 + threadIdx.x;       // quad index
  int row = i >> 5, k4 = (i & 31) * 4;
  if (row >= nrow) return;
  float4 v = *(const float4*)(in + (size_t)row * 128 + k4);
  ushort4 h4, l4;
  f2hilo(v.x, h4.x, l4.x); f2hilo(v.y, h4.y, l4.y);
  f2hilo(v.z, h4.z, l4.z); f2hilo(v.w, h4.w, l4.w);
  size_t off = pk_off(row, k4, 4);              // w in {0,4}: ushort4 stays in-chunk
  *(ushort4*)(hi + off) = h4;
  *(ushort4*)(lo + off) = l4;
}

// ---------- one-shot weight prep: transpose/permute + PACKED bf16 (hi only) ----------
// Reads coalesced over n. W_ih/W_hh rows PERMUTED to gate-interleaved layout:
// orig row (gate*256+ch) -> n' = (ch>>4)*64 + gate*16 + (ch&15) (epilogue LSTM fusion).
__global__ __launch_bounds__(256) void prep_w(const float* __restrict__ Win,
    const float* __restrict__ Wsrc, const float* __restrict__ Wih,
    const float* __restrict__ Whh, const float* __restrict__ Wout,
    u16* WinH, u16* WsH, u16* IhH, u16* HhH, u16* WoH){
  int idx = blockIdx.x * 256 + threadIdx.x;
  float v; u16 *ph; size_t off;
  if (idx < 32768){                       // WinT [256][128] <- Win[128][256]; nbk=4
    int n = idx & 255, k = idx >> 8;
    v = Win[k * 256 + n]; ph = WinH; off = pk_off(n, k, 4);
  } else if (idx < 229376){               // WsT [3][256][256] <- Wsrc^T; nbk=8
    int t = idx - 32768; int hop = t >> 16, r = t & 65535, n = r & 255, k = r >> 8;
    v = Wsrc[hop * 65536 + k * 256 + n]; ph = WsH;
    off = (size_t)hop * 65536 + pk_off(n, k, 8);
  } else if (idx < 1015808){              // W_ih [3][1024][256], gate-interleaved; nbk=8
    int t = idx - 229376;
    int hop = t >> 18, r = (t >> 8) & 1023, k = t & 255;
    int gate = r >> 8, ch = r & 255;
    int np = ((ch >> 4) << 6) + (gate << 4) + (ch & 15);
    v = Wih[t]; ph = IhH;
    off = (size_t)hop * 262144 + pk_off(np, k, 8);
  } else if (idx < 1802240){              // W_hh, same permutation
    int t = idx - 1015808;
    int hop = t >> 18, r = (t >> 8) & 1023, k = t & 255;
    int gate = r >> 8, ch = r & 255;
    int np = ((ch >> 4) << 6) + (gate << 4) + (ch & 15);
    v = Whh[t]; ph = HhH;
    off = (size_t)hop * 262144 + pk_off(np, k, 8);
  } else if (idx < 1835008){              // WoT [128][256] <- Wout^T; nbk=8
    int t = idx - 1802240; int n = t & 127, k = t >> 7;
    v = Wout[k * 128 + n]; ph = WoH; off = pk_off(n, k, 8);
  } else return;
  ph[off] = bf16_rne(v);
}

// ---------- w_s[hop] = Wsrc[hop]@a_s, w_d[hop] = Wdst[hop]@a_d (row dots, f32) ----------
__global__ __launch_bounds__(256) void prep_wvec(const float* __restrict__ Wsrc,
    const float* __restrict__ Wdst, const float* __restrict__ as_,
    const float* __restrict__ ad_, float* __restrict__ wsv, float* __restrict__ wdv){
  int wid = blockIdx.x * 4 + (threadIdx.x >> 6), lane = threadIdx.x & 63;
  if (wid >= 6 * 256) return;
  int vec = wid >> 8, i = wid & 255;
  int hop = vec >> 1; bool isd = vec & 1;
  const float* Wrow = (isd ? Wdst : Wsrc) + (size_t)hop * 65536 + (size_t)i * 256;
  const float* a = (isd ? ad_ : as_) + hop * 256;
  float4 w4 = *(const float4*)(Wrow + lane * 4);
  float4 a4 = *(const float4*)(a + lane * 4);
  float v = w4.x * a4.x + w4.y * a4.y + w4.z * a4.z + w4.w * a4.w;
  #pragma unroll
  for (int off = 32; off; off >>= 1) v += __shfl_down(v, off);
  if (!lane) (isd ? wdv : wsv)[hop * 256 + i] = v;
}

// ---------- alpha from LINEAR bf16-hi x: coalesced ushort4 row reads ----------
// Rows < nd need BOTH the src-dot (vs wsv) and dst-dot (vs wdv): one row pass.
__global__ __launch_bounds__(256) void alpha_mv(const u16* __restrict__ xH,
    const float* __restrict__ wsv, const float* __restrict__ wdv,
    float* __restrict__ as_out, float* __restrict__ ad_out, int ns, int nd){
  int row = blockIdx.x * 4 + (threadIdx.x >> 6), lane = threadIdx.x & 63;
  if (row >= ns) return;
  ushort4 w = *(const ushort4*)(xH + (size_t)row * 256 + lane * 4);
  float x0 = bf16_to_f(w.x), x1 = bf16_to_f(w.y), x2 = bf16_to_f(w.z), x3 = bf16_to_f(w.w);
  float4 s4 = *(const float4*)(wsv + lane * 4);
  float vs = x0 * s4.x + x1 * s4.y + x2 * s4.z + x3 * s4.w;
  bool both = row < nd;
  float vd = 0.f;
  if (both){
    float4 d4 = *(const float4*)(wdv + lane * 4);
    vd = x0 * d4.x + x1 * d4.y + x2 * d4.z + x3 * d4.w;
  }
  #pragma unroll
  for (int off2 = 32; off2; off2 >>= 1){
    vs += __shfl_down(vs, off2);
    vd += __shfl_down(vd, off2);
  }
  if (!lane){
    as_out[row] = vs;
    if (both) ad_out[row] = vd;
  }
}

// ---------- edges + self-loops: leaky-relu alpha -> e=exp(alpha) directly, degree ----
// NO-MAX softmax (round-12, exact up to fp noise: alphas O(1), softmax shift-invariant)
__global__ __launch_bounds__(256) void edge_a(const int* __restrict__ src,
    const int* __restrict__ dst, const float* __restrict__ as_, const float* __restrict__ ad_,
    float* __restrict__ e_edge, float* __restrict__ e_self,
    int* __restrict__ cnt, int E, int nd){
  int i = blockIdx.x * 256 + threadIdx.x;
  if (i < E){
    int s = src[i], d = dst[i];
    float al = as_[s] + ad_[d];
    al = al > 0.f ? al : NEG_SLOPE * al;
    e_edge[i] = expf(al);
    atomicAdd(&cnt[d], 1);
  } else if (i < E + nd){
    int j = i - E;
    float al = as_[j] + ad_[j];
    al = al > 0.f ? al : NEG_SLOPE * al;
    e_self[j] = expf(al);
  }
}

// ---------- scan, 2 dispatches ----------
__global__ __launch_bounds__(256) void scan_part(const int* __restrict__ cnt,
    int* __restrict__ part, int n){
  __shared__ int ws_[4];
  int lane = threadIdx.x & 63, wv = threadIdx.x >> 6;
  int i = blockIdx.x * 256 + threadIdx.x;
  int v = (i < n) ? cnt[i] : 0;
  #pragma unroll
  for (int off = 32; off; off >>= 1) v += __shfl_down(v, off);
  if (!lane) ws_[wv] = v;
  __syncthreads();
  if (!threadIdx.x) part[blockIdx.x] = ws_[0] + ws_[1] + ws_[2] + ws_[3];
}
__global__ __launch_bounds__(256) void scan_fin(const int* __restrict__ cnt,
    const int* __restrict__ part, int* __restrict__ base, int* __restrict__ cursor,
    int n, int nb){
  __shared__ int ps[128];
  __shared__ int wtot[4];
  int t = threadIdx.x;
  if (t < 128) ps[t] = (t < nb) ? part[t] : 0;
  __syncthreads();
  #pragma unroll
  for (int off = 1; off < 128; off <<= 1){
    int v = (t < 128 && t >= off) ? ps[t - off] : 0;
    __syncthreads();
    if (t < 128) ps[t] += v;
    __syncthreads();
  }
  int lane = t & 63, wv = t >> 6;
  int i = blockIdx.x * 256 + t;
  int v = (i < n) ? cnt[i] : 0;
  int incl = v;
  #pragma unroll
  for (int off = 1; off < 64; off <<= 1){
    int s = __shfl_up(incl, off);
    if (lane >= off) incl += s;
  }
  if (lane == 63) wtot[wv] = incl;
  __syncthreads();
  int woff = blockIdx.x ? ps[blockIdx.x - 1] : 0;
  for (int w = 0; w < wv; w++) woff += wtot[w];
  int excl = woff + incl - v;
  if (i < n){ base[i] = excl; cursor[i] = excl; }
}

// ---------- CSR fill (e already computed in edge_a) ----------
__global__ __launch_bounds__(256) void edge_b(const int* __restrict__ src,
    const int* __restrict__ dst, const float* __restrict__ e_edge,
    int* __restrict__ cursor, int* __restrict__ csr_src, float* __restrict__ csr_e, int E){
  int e = blockIdx.x * 256 + threadIdx.x;
  if (e >= E) return;
  int d = dst[e];
  int pos = atomicAdd(&cursor[d], 1);
  csr_src[pos] = src[e];
  csr_e[pos] = e_edge[e];
}

// ---------- gather: agg[j] = (sum_e w_e x[src] + w_self x[j]) / sum w ----------
// x from LINEAR bf16-hi u16 rows (512B contiguous per edge, coalesced ushort4/lane —
// HALF the traffic of the u32 interleaved rows) with 8-deep independent-load unroll.
// f32 accumulate; output packed hi/lo (GEMM A-operand keeps ~17-bit precision).
__global__ __launch_bounds__(256) void gather_agg(const u16* __restrict__ xH,
    const int* __restrict__ base, const int* __restrict__ cnt,
    const int* __restrict__ csr_src, const float* __restrict__ csr_e,
    const float* __restrict__ e_self,
    u16* __restrict__ aggH, u16* __restrict__ aggL, int n){
  int wv = threadIdx.x >> 6, lane = threadIdx.x & 63;
  int j = blockIdx.x * 4 + wv;
  if (j >= n) return;
  int b0 = base[j], cn = cnt[j];
  float a0 = 0.f, a1 = 0.f, a2 = 0.f, a3 = 0.f, ds = 0.f;
  int k = 0;
  for (; k + 8 <= cn; k += 8){
    int ss[8]; float ee[8]; ushort4 ww[8];
    #pragma unroll
    for (int u = 0; u < 8; u++){ ss[u] = csr_src[b0 + k + u]; ee[u] = csr_e[b0 + k + u]; }
    #pragma unroll
    for (int u = 0; u < 8; u++) ww[u] = *(const ushort4*)(xH + (size_t)ss[u] * 256 + lane * 4);
    #pragma unroll
    for (int u = 0; u < 8; u++){
      float e = ee[u];
      a0 += e * bf16_to_f(ww[u].x); a1 += e * bf16_to_f(ww[u].y);
      a2 += e * bf16_to_f(ww[u].z); a3 += e * bf16_to_f(ww[u].w);
      ds += e;
    }
  }
  for (; k < cn; k++){
    int s = csr_src[b0 + k];
    float e = csr_e[b0 + k];
    ushort4 w = *(const ushort4*)(xH + (size_t)s * 256 + lane * 4);
    a0 += e * bf16_to_f(w.x); a1 += e * bf16_to_f(w.y);
    a2 += e * bf16_to_f(w.z); a3 += e * bf16_to_f(w.w);
    ds += e;
  }
  float es = e_self[j];
  {
    ushort4 w = *(const ushort4*)(xH + (size_t)j * 256 + lane * 4);
    a0 += es * bf16_to_f(w.x); a1 += es * bf16_to_f(w.y);
    a2 += es * bf16_to_f(w.z); a3 += es * bf16_to_f(w.w);
    ds += es;
  }
  float inv = 1.f / ds;
  ushort4 H4, L4;
  f2hilo(a0 * inv, H4.x, L4.x); f2hilo(a1 * inv, H4.y, L4.y);
  f2hilo(a2 * inv, H4.z, L4.z); f2hilo(a3 * inv, H4.w, L4.w);
  size_t off = pk_off(j, lane * 4, 8);
  *(ushort4*)(aggH + off) = H4;
  *(ushort4*)(aggL + off) = L4;
}

extern "C" void kernel_launch(void* const* d_in, const int* in_sizes, int n_in,
                              void* d_out, int out_size, void* d_ws, size_t ws_size,
                              hipStream_t stream){
  const float* feats   = (const float*)d_in[0];
  const float* Win     = (const float*)d_in[1];
  const float* b_in    = (const float*)d_in[2];
  const float* Wsrc    = (const float*)d_in[3];
  const float* Wdst    = (const float*)d_in[4];
  const float* att_src = (const float*)d_in[5];
  const float* att_dst = (const float*)d_in[6];
  const float* gat_b   = (const float*)d_in[7];
  const float* W_ih    = (const float*)d_in[8];
  const float* W_hh    = (const float*)d_in[9];
  const float* Wout    = (const float*)d_in[10];
  const float* b_out   = (const float*)d_in[11];
  const int* srcs[3] = {(const int*)d_in[12], (const int*)d_in[14], (const int*)d_in[16]};
  const int* dsts[3] = {(const int*)d_in[13], (const int*)d_in[15], (const int*)d_in[17]};
  (void)in_sizes; (void)n_in; (void)out_size; (void)ws_size;

  const int ns_a[3] = {60000, 30000, 15000};
  const int nd_a[3] = {30000, 15000, 7500};
  const int E_a[3]  = {480000, 240000, 120000};

  // ---- workspace layout (~200 MiB), aliasing lifetime-checked ----
  char* w = (char*)d_ws;
  u16* xH      = (u16*)(w + 0);                   // linear bf16-hi x rows, 60032x256 u16 (30.7MB)
  u16* featsH  = (u16*)(w + 61500000);            // packed 60032x128; dead after inproj
  u16* featsL  = (u16*)(w + 77000000);
  float* c     = (float*)(w + 61500000);          // [30000][256] f32; alias feats
                                                  // (feats dead after inproj; c first written hop0 gates)
  u16* aggH    = (u16*)(w + 92500000);            // packed 30080x256
  u16* aggL    = (u16*)(w + 108000000);
  u16* hAH     = (u16*)(w + 123500000);           // packed h ping-pong A
  u16* hAL     = (u16*)(w + 139000000);
  u16* hBH     = (u16*)(w + 154500000);           // set B
  u16* hBL     = (u16*)(w + 170000000);
  u16* xbH     = (u16*)(w + 185500000);
  u16* xbL     = (u16*)(w + 201000000);
  u16* WinH = (u16*)(w + 216500000);              // weight hi-only (2-phase GEMM)
  u16* WsH  = WinH + 32768;
  u16* IhH  = WsH + 196608;
  u16* HhH  = IhH + 786432;
  u16* WoH  = HhH + 786432;
  float* wsv = (float*)(w + 224200000); float* wdv = wsv + 768;
  float* alpha_s = wdv + 768;
  float* alpha_d = alpha_s + 60000;
  float* e_edge  = alpha_d + 30000;               // per-edge exp(alpha)
  float* e_self  = e_edge + 480000;               // per-node self exp(alpha)
  int* cnt       = (int*)(e_self + 30000);
  int* base      = cnt + 30000;
  int* cursor    = base + 30000;
  int* part      = cursor + 30000;                // scan partials (<=128)
  int* csr_src   = part + 256;
  float* csr_e   = (float*)(csr_src + 480000);

  // ---- one-time prep (inputs only) ----
  prep_w<<<7168, 256, 0, stream>>>(Win, Wsrc, W_ih, W_hh, Wout,
      WinH, WsH, IhH, HhH, WoH);
  prep_wvec<<<384, 256, 0, stream>>>(Wsrc, Wdst, att_src, att_dst, wsv, wdv);
  cvt_feats<<<7500, 256, 0, stream>>>(feats, featsH, featsL, 60000);

  // ---- input projection: x0 (linear bf16-hi) = feats @ Win + b_in ----
  {
    dim3 g(PAD8(CDIV(60000, 128)), 2);
    mfma_gemm<<<g, 256, 0, stream>>>(featsH, featsL, WinH,
        nullptr, nullptr, nullptr, 1, 60000, 256, 128,
        b_in, nullptr, nullptr, nullptr, xH, nullptr, nullptr,
        nullptr, nullptr, nullptr, 0, 0);
  }

  u16* hCurH = hAH; u16* hCurL = hAL;   // packed h from previous hop (pair-1 A-op)
  for (int hop = 0; hop < 3; hop++){
    const int ns = ns_a[hop], nd = nd_a[hop], E = E_a[hop];
    const int nb = CDIV(nd, 256);
    hipMemsetAsync(cnt, 0, (size_t)nd * 4, stream);

    alpha_mv<<<CDIV(ns, 4), 256, 0, stream>>>(xH, wsv + hop * 256, wdv + hop * 256,
        alpha_s, alpha_d, ns, nd);
    edge_a<<<CDIV(E + nd, 256), 256, 0, stream>>>(srcs[hop], dsts[hop], alpha_s, alpha_d,
        e_edge, e_self, cnt, E, nd);
    scan_part<<<nb, 256, 0, stream>>>(cnt, part, nd);
    scan_fin<<<nb, 256, 0, stream>>>(cnt, part, base, cursor, nd, nb);
    edge_b<<<CDIV(E, 256), 256, 0, stream>>>(srcs[hop], dsts[hop], e_edge,
        cursor, csr_src, csr_e, E);
    gather_agg<<<CDIV(nd, 4), 256, 0, stream>>>(xH, base, cnt, csr_src, csr_e,
        e_self, aggH, aggL, nd);

    // xb(packed) = tanh(agg @ WsrcT + gat_b)   [M = nd rows]
    {
      dim3 g(PAD8(CDIV(nd, 128)), 2);
      mfma_gemm<<<g, 256, 0, stream>>>(aggH, aggL, WsH + (size_t)hop * 65536,
          nullptr, nullptr, nullptr, 1, nd, 256, 256,
          gat_b + hop * 256, nullptr, xbH, xbL, nullptr, nullptr, nullptr,
          nullptr, nullptr, nullptr, 0, 1);
    }

    // gates GEMM + fused LSTM; h: packed ping-pong (A-op) + linear bf16-hi xH
    // (next hop's gather/alpha; dead after hop 1 -> skip at hop 2)
    u16* hNewH = (hop == 0) ? hAH : (hCurH == hAH ? hBH : hAH);
    u16* hNewL = (hop == 0) ? hAL : (hCurL == hAL ? hBL : hAL);
    {
      dim3 g(PAD8(CDIV(nd, 128)), 8);
      mfma_gemm<<<g, 256, 0, stream>>>(xbH, xbL, IhH + (size_t)hop * 262144,
          hCurH, hCurL, HhH + (size_t)hop * 262144,
          hop ? 2 : 1, nd, 1024, 256,
          nullptr, nullptr, nullptr, nullptr, nullptr,
          c, c, hNewH, hNewL, hop < 2 ? xH : nullptr, hop == 0 ? 1 : 0, 0);
    }
    hCurH = hNewH; hCurL = hNewL;
  }

  // ---- output projection (N=128): d_out = h @ Wout + b_out ----
  {
    dim3 g(PAD8(CDIV(7500, 128)), 1);
    mfma_gemm<<<g, 256, 0, stream>>>(hCurH, hCurL, WoH,
        nullptr, nullptr, nullptr, 1, 7500, 128, 256,
        b_out, (float*)d_out, nullptr, nullptr, nullptr, nullptr, nullptr,
        nullptr, nullptr, nullptr, 0, 0);
  }
}